// Round 1
// baseline (1106.548 us; speedup 1.0000x reference)
//
#include <hip/hip_runtime.h>
#include <math.h>

#define N_NODES 100000
#define N_EDGES 3200000
#define N_GRAPHS 512

// ---------------- CSR build ----------------

__global__ void count_kernel(const int* __restrict__ dst, int* __restrict__ cnt, int E) {
    int e = blockIdx.x * blockDim.x + threadIdx.x;
    if (e < E) atomicAdd(&cnt[dst[e]], 1);
}

__global__ void dinv_kernel(const int* __restrict__ cnt, float* __restrict__ dinv, int n) {
    int i = blockIdx.x * blockDim.x + threadIdx.x;
    if (i < n) dinv[i] = 1.0f / sqrtf((float)(cnt[i] + 1));  // +1 self loop, always > 0
}

#define SCAN_T 256
#define SCAN_I 4   // items per thread -> 1024 per block

__global__ void scan1_kernel(const int* __restrict__ cnt, int* __restrict__ off,
                             int* __restrict__ bsum, int n) {
    __shared__ int sh[SCAN_T];
    int tid = threadIdx.x;
    int base = blockIdx.x * SCAN_T * SCAN_I + tid * SCAN_I;
    int v[SCAN_I];
    int s = 0;
#pragma unroll
    for (int i = 0; i < SCAN_I; ++i) {
        int idx = base + i;
        v[i] = (idx < n) ? cnt[idx] : 0;
        s += v[i];
    }
    sh[tid] = s;
    __syncthreads();
    for (int st = 1; st < SCAN_T; st <<= 1) {
        int t = (tid >= st) ? sh[tid - st] : 0;
        __syncthreads();
        sh[tid] += t;
        __syncthreads();
    }
    int excl = sh[tid] - s;
    if (tid == SCAN_T - 1) bsum[blockIdx.x] = sh[tid];
    int run = excl;
#pragma unroll
    for (int i = 0; i < SCAN_I; ++i) {
        int idx = base + i;
        if (idx < n) off[idx] = run;
        run += v[i];
    }
}

__global__ void scan2_kernel(int* __restrict__ bsum, int nb, int* __restrict__ offN, int E) {
    if (threadIdx.x == 0 && blockIdx.x == 0) {
        int run = 0;
        for (int i = 0; i < nb; ++i) { int t = bsum[i]; bsum[i] = run; run += t; }
        *offN = E;
    }
}

__global__ void scan3_kernel(const int* __restrict__ bsum, int* __restrict__ off,
                             int* __restrict__ cur, int n) {
    int b = blockIdx.x;
    int s = bsum[b];
    int base = b * SCAN_T * SCAN_I;
    for (int i = threadIdx.x; i < SCAN_T * SCAN_I; i += SCAN_T) {
        int idx = base + i;
        if (idx < n) {
            int v = off[idx] + s;
            off[idx] = v;
            cur[idx] = v;
        }
    }
}

__global__ void fill_kernel(const int* __restrict__ src, const int* __restrict__ dst,
                            const float* __restrict__ dinv, int* __restrict__ cur,
                            int* __restrict__ col, float* __restrict__ nrm, int E) {
    int e = blockIdx.x * blockDim.x + threadIdx.x;
    if (e < E) {
        int d = dst[e], s = src[e];
        int pos = atomicAdd(&cur[d], 1);
        col[pos] = s;
        nrm[pos] = dinv[s] * dinv[d];
    }
}

// ---------------- dense linear: Y[n,64] = X[n,K] @ W[K,64] ----------------

template <int K>
__global__ __launch_bounds__(256) void lin_kernel(const float* __restrict__ X,
                                                  const float* __restrict__ W,
                                                  float* __restrict__ Y) {
    __shared__ float Ws[K * 64];
    __shared__ float Xs[32 * K];
    int tid = threadIdx.x;
    for (int i = tid * 4; i < K * 64; i += 256 * 4)
        *reinterpret_cast<float4*>(&Ws[i]) = *reinterpret_cast<const float4*>(&W[i]);
    int row0 = blockIdx.x * 32;
    const float* Xbase = X + (size_t)row0 * K;
    for (int i = tid * 4; i < 32 * K; i += 256 * 4)
        *reinterpret_cast<float4*>(&Xs[i]) = *reinterpret_cast<const float4*>(&Xbase[i]);
    __syncthreads();

    int wid = tid >> 6, lane = tid & 63;
    int rbase = wid * 8;
    float acc[8];
#pragma unroll
    for (int r = 0; r < 8; ++r) acc[r] = 0.f;

    for (int k4 = 0; k4 < K / 4; ++k4) {
        float w0 = Ws[(k4 * 4 + 0) * 64 + lane];
        float w1 = Ws[(k4 * 4 + 1) * 64 + lane];
        float w2 = Ws[(k4 * 4 + 2) * 64 + lane];
        float w3 = Ws[(k4 * 4 + 3) * 64 + lane];
#pragma unroll
        for (int r = 0; r < 8; ++r) {
            float4 xv = *reinterpret_cast<const float4*>(&Xs[(rbase + r) * K + k4 * 4]);
            acc[r] += xv.x * w0 + xv.y * w1 + xv.z * w2 + xv.w * w3;
        }
    }
#pragma unroll
    for (int r = 0; r < 8; ++r)
        Y[(size_t)(row0 + rbase + r) * 64 + lane] = acc[r];
}

// ---------------- aggregation: one wave per node, lane = channel ----------------

template <bool RELU>
__global__ __launch_bounds__(256) void agg_kernel(const float* __restrict__ T,
                                                  const int* __restrict__ off,
                                                  const int* __restrict__ col,
                                                  const float* __restrict__ nrm,
                                                  const float* __restrict__ dinv,
                                                  const float* __restrict__ bias,
                                                  float* __restrict__ H, int n) {
    int wid = threadIdx.x >> 6, lane = threadIdx.x & 63;
    int node = blockIdx.x * 4 + wid;
    if (node >= n) return;
    float di = dinv[node];
    float acc = T[(size_t)node * 64 + lane] * (di * di);  // self loop
    int beg = off[node], end = off[node + 1];
    for (int e = beg; e < end; ++e) {
        int s = col[e];
        float w = nrm[e];
        acc += T[(size_t)s * 64 + lane] * w;
    }
    acc += bias[lane];
    if (RELU) acc = fmaxf(acc, 0.f);
    H[(size_t)node * 64 + lane] = acc;
}

// ---------------- pooling: sorted batch, segmented wave reduction ----------------

__global__ __launch_bounds__(256) void pool_kernel(const float* __restrict__ H,
                                                   const int* __restrict__ batch,
                                                   float* __restrict__ pooled,
                                                   int* __restrict__ cntg,
                                                   int n, int chunk) {
    int wid_g = blockIdx.x * 4 + (threadIdx.x >> 6);
    int lane = threadIdx.x & 63;
    int start = wid_g * chunk;
    if (start >= n) return;
    int end = min(n, start + chunk);
    int g_cur = batch[start];
    float acc = 0.f;
    int c_loc = 0;
    for (int i = start; i < end; ++i) {
        int g = batch[i];
        if (g != g_cur) {
            atomicAdd(&pooled[g_cur * 64 + lane], acc);
            if (lane == 0) atomicAdd(&cntg[g_cur], c_loc);
            acc = 0.f; c_loc = 0; g_cur = g;
        }
        acc += H[(size_t)i * 64 + lane];
        c_loc++;
    }
    atomicAdd(&pooled[g_cur * 64 + lane], acc);
    if (lane == 0) atomicAdd(&cntg[g_cur], c_loc);
}

// ---------------- head: mean, MLP (folded), softmax over graphs ----------------

__global__ __launch_bounds__(512) void head_kernel(const float* __restrict__ pooled,
                                                   const int* __restrict__ cntg,
                                                   const float* __restrict__ Wl1,
                                                   const float* __restrict__ bl1,
                                                   const float* __restrict__ Wl2,
                                                   const float* __restrict__ bl2,
                                                   float* __restrict__ out) {
    __shared__ float Weff[64 * 2];
    __shared__ float beff[2];
    __shared__ float red[512];
    int tid = threadIdx.x;
    if (tid < 128) {
        int c = tid >> 1, j = tid & 1;
        float s = 0.f;
        for (int k = 0; k < 32; ++k) s += Wl1[c * 32 + k] * Wl2[k * 2 + j];
        Weff[c * 2 + j] = s;
    }
    if (tid < 2) {
        float s = bl2[tid];
        for (int k = 0; k < 32; ++k) s += bl1[k] * Wl2[k * 2 + tid];
        beff[tid] = s;
    }
    __syncthreads();

    int g = tid;
    float cn = fmaxf((float)cntg[g], 1.f);
    float z0 = beff[0], z1 = beff[1];
    for (int c = 0; c < 64; ++c) {
        float p = pooled[g * 64 + c] / cn;
        z0 += p * Weff[c * 2 + 0];
        z1 += p * Weff[c * 2 + 1];
    }

    // softmax over g (axis=0), column 0
    red[tid] = z0; __syncthreads();
    for (int s = 256; s > 0; s >>= 1) { if (tid < s) red[tid] = fmaxf(red[tid], red[tid + s]); __syncthreads(); }
    float m0 = red[0]; __syncthreads();
    float e0 = expf(z0 - m0);
    red[tid] = e0; __syncthreads();
    for (int s = 256; s > 0; s >>= 1) { if (tid < s) red[tid] += red[tid + s]; __syncthreads(); }
    float s0 = red[0]; __syncthreads();
    out[g * 2 + 0] = e0 / s0;

    // column 1
    red[tid] = z1; __syncthreads();
    for (int s = 256; s > 0; s >>= 1) { if (tid < s) red[tid] = fmaxf(red[tid], red[tid + s]); __syncthreads(); }
    float m1 = red[0]; __syncthreads();
    float e1 = expf(z1 - m1);
    red[tid] = e1; __syncthreads();
    for (int s = 256; s > 0; s >>= 1) { if (tid < s) red[tid] += red[tid + s]; __syncthreads(); }
    float s1 = red[0]; __syncthreads();
    out[g * 2 + 1] = e1 / s1;
}

// ---------------- launch ----------------

extern "C" void kernel_launch(void* const* d_in, const int* in_sizes, int n_in,
                              void* d_out, int out_size, void* d_ws, size_t ws_size,
                              hipStream_t stream) {
    const float* x   = (const float*)d_in[0];
    const int*   ei  = (const int*)d_in[1];
    const int*   bat = (const int*)d_in[2];
    const float* W1  = (const float*)d_in[3];
    const float* b1  = (const float*)d_in[4];
    const float* W2  = (const float*)d_in[5];
    const float* b2  = (const float*)d_in[6];
    const float* Wl1 = (const float*)d_in[7];
    const float* bl1 = (const float*)d_in[8];
    const float* Wl2 = (const float*)d_in[9];
    const float* bl2 = (const float*)d_in[10];
    float* out = (float*)d_out;

    const int N = N_NODES, E = N_EDGES;
    const int* src = ei;
    const int* dst = ei + E;

    // workspace carve-out (256B aligned chunks)
    size_t o = 0;
    auto alloc = [&](size_t bytes) {
        void* p = (char*)d_ws + o;
        o += (bytes + 255) / 256 * 256;
        return p;
    };
    int*   cnt    = (int*)alloc((size_t)N * 4);
    int*   off    = (int*)alloc((size_t)(N + 1) * 4);
    int*   cur    = (int*)alloc((size_t)(N + 1) * 4);
    float* dinv   = (float*)alloc((size_t)N * 4);
    int*   col    = (int*)alloc((size_t)E * 4);
    float* nrm    = (float*)alloc((size_t)E * 4);
    float* T      = (float*)alloc((size_t)N * 64 * 4);
    float* H      = (float*)alloc((size_t)N * 64 * 4);
    float* pooled = (float*)alloc((size_t)N_GRAPHS * 64 * 4);
    int*   cntg   = (int*)alloc((size_t)N_GRAPHS * 4);
    int*   bsum   = (int*)alloc(256 * 4);

    // zero the atomic targets (ws is NOT re-poisoned between replays; must be per-call)
    hipMemsetAsync(cnt, 0, (size_t)N * 4, stream);
    hipMemsetAsync(pooled, 0, (size_t)N_GRAPHS * 64 * 4, stream);
    hipMemsetAsync(cntg, 0, (size_t)N_GRAPHS * 4, stream);

    // CSR build
    int eblocks = (E + 255) / 256;
    count_kernel<<<eblocks, 256, 0, stream>>>(dst, cnt, E);
    dinv_kernel<<<(N + 255) / 256, 256, 0, stream>>>(cnt, dinv, N);
    int nscan = (N + SCAN_T * SCAN_I - 1) / (SCAN_T * SCAN_I);
    scan1_kernel<<<nscan, SCAN_T, 0, stream>>>(cnt, off, bsum, N);
    scan2_kernel<<<1, 64, 0, stream>>>(bsum, nscan, off + N, E);
    scan3_kernel<<<nscan, SCAN_T, 0, stream>>>(bsum, off, cur, N);
    fill_kernel<<<eblocks, 256, 0, stream>>>(src, dst, dinv, cur, col, nrm, E);

    // layer 1: T = x @ W1 ; H = relu(agg(T) + b1)
    lin_kernel<128><<<N / 32, 256, 0, stream>>>(x, W1, T);
    agg_kernel<true><<<(N + 3) / 4, 256, 0, stream>>>(T, off, col, nrm, dinv, b1, H, N);

    // layer 2: T = H @ W2 ; H = agg(T) + b2
    lin_kernel<64><<<N / 32, 256, 0, stream>>>(H, W2, T);
    agg_kernel<false><<<(N + 3) / 4, 256, 0, stream>>>(T, off, col, nrm, dinv, b2, H, N);

    // pooling
    int chunk = (N + 511) / 512;  // 512 waves
    pool_kernel<<<128, 256, 0, stream>>>(H, bat, pooled, cntg, N, chunk);

    // head + softmax over graphs
    head_kernel<<<1, 512, 0, stream>>>(pooled, cntg, Wl1, bl1, Wl2, bl2, out);
}

// Round 2
// 536.506 us; speedup vs baseline: 2.0625x; 2.0625x over previous
//
#include <hip/hip_runtime.h>
#include <math.h>

#define N_NODES 100000
#define N_EDGES 3200000
#define N_GRAPHS 512

#define BSHIFT 8
#define BSPAN 256                      // nodes per bucket
#define NB 391                         // ceil(N_NODES / BSPAN)
#define A_ITEMS 8
#define A_TILE (A_ITEMS * 256)         // edges per scatter block

// ---------- pass A1: global bucket histogram ----------
__global__ __launch_bounds__(256) void bhist_kernel(const int* __restrict__ dst,
                                                    int* __restrict__ bcnt, int E) {
    __shared__ int h[NB];
    int tid = threadIdx.x;
    for (int b = tid; b < NB; b += 256) h[b] = 0;
    __syncthreads();
    int base = blockIdx.x * A_TILE;
    for (int i = 0; i < A_ITEMS; ++i) {
        int e = base + i * 256 + tid;
        if (e < E) atomicAdd(&h[dst[e] >> BSHIFT], 1);
    }
    __syncthreads();
    for (int b = tid; b < NB; b += 256)
        if (h[b]) atomicAdd(&bcnt[b], h[b]);
}

// ---------- pass A1.5: scan buckets -> bases + cursors ----------
__global__ __launch_bounds__(512) void bscan_kernel(const int* __restrict__ bcnt,
                                                    int* __restrict__ bbase,
                                                    int* __restrict__ cursor,
                                                    int* __restrict__ offN, int E) {
    __shared__ int s[512];
    int tid = threadIdx.x;
    int v = (tid < NB) ? bcnt[tid] : 0;
    s[tid] = v;
    __syncthreads();
    for (int st = 1; st < 512; st <<= 1) {
        int t = (tid >= st) ? s[tid - st] : 0;
        __syncthreads();
        s[tid] += t;
        __syncthreads();
    }
    int excl = s[tid] - v;
    if (tid < NB) { bbase[tid] = excl; cursor[tid] = excl; }
    if (tid == NB - 1) bbase[NB] = excl + v;
    if (tid == 0) *offN = E;
}

// ---------- pass A2: scatter edges into bucket segments ----------
__global__ __launch_bounds__(256) void scatter_kernel(const int* __restrict__ src,
                                                      const int* __restrict__ dst,
                                                      int* __restrict__ cursor,
                                                      int2* __restrict__ pairs, int E) {
    __shared__ int hcnt[NB];
    __shared__ int hbase[NB];
    int tid = threadIdx.x;
    for (int b = tid; b < NB; b += 256) hcnt[b] = 0;
    __syncthreads();
    int base = blockIdx.x * A_TILE;
    int sv[A_ITEMS], dv[A_ITEMS], rk[A_ITEMS];
    for (int i = 0; i < A_ITEMS; ++i) {
        int e = base + i * 256 + tid;
        if (e < E) {
            sv[i] = src[e];
            dv[i] = dst[e];
            rk[i] = atomicAdd(&hcnt[dv[i] >> BSHIFT], 1);
        } else dv[i] = -1;
    }
    __syncthreads();
    for (int b = tid; b < NB; b += 256) {
        int c = hcnt[b];
        if (c) hbase[b] = atomicAdd(&cursor[b], c);
    }
    __syncthreads();
    for (int i = 0; i < A_ITEMS; ++i) {
        if (dv[i] >= 0) {
            int b = dv[i] >> BSHIFT;
            pairs[hbase[b] + rk[i]] = make_int2(sv[i], dv[i]);
        }
    }
}

// ---------- pass B: per-bucket fine sort -> col, off, dinv ----------
__global__ __launch_bounds__(256) void bucket_kernel(const int2* __restrict__ pairs,
                                                     const int* __restrict__ bbase,
                                                     int* __restrict__ col,
                                                     int* __restrict__ off,
                                                     float* __restrict__ dinv, int N) {
    __shared__ int ncnt[BSPAN];
    __shared__ int nbase[BSPAN];
    __shared__ int a[BSPAN];
    int b = blockIdx.x, tid = threadIdx.x;
    int base = bbase[b];
    int cntb = bbase[b + 1] - base;
    int n0 = b << BSHIFT;
    int nn = min(BSPAN, N - n0);
    ncnt[tid] = 0;
    __syncthreads();
    for (int i = tid; i < cntb; i += 256)
        atomicAdd(&ncnt[pairs[base + i].y - n0], 1);
    __syncthreads();
    int v = ncnt[tid];
    a[tid] = v;
    __syncthreads();
    for (int st = 1; st < 256; st <<= 1) {
        int t = (tid >= st) ? a[tid - st] : 0;
        __syncthreads();
        a[tid] += t;
        __syncthreads();
    }
    nbase[tid] = a[tid] - v;
    if (tid < nn) {
        off[n0 + tid] = base + nbase[tid];
        dinv[n0 + tid] = rsqrtf((float)(v + 1));   // +1 self loop
    }
    ncnt[tid] = 0;   // reuse as cursor
    __syncthreads();
    for (int i = tid; i < cntb; i += 256) {
        int2 p = pairs[base + i];
        int dl = p.y - n0;
        int pos = base + nbase[dl] + atomicAdd(&ncnt[dl], 1);
        col[pos] = p.x;
    }
}

// ---------- dense linear: U[n,64] = dinv[n] * (X[n,K] @ W[K,64]) ----------
template <int K>
__global__ __launch_bounds__(256) void lin_kernel(const float* __restrict__ X,
                                                  const float* __restrict__ W,
                                                  const float* __restrict__ rs,
                                                  float* __restrict__ U) {
    __shared__ float Ws[K * 64];
    __shared__ float Xs[32 * K];
    int tid = threadIdx.x;
    for (int i = tid * 4; i < K * 64; i += 256 * 4)
        *reinterpret_cast<float4*>(&Ws[i]) = *reinterpret_cast<const float4*>(&W[i]);
    int row0 = blockIdx.x * 32;
    const float* Xbase = X + (size_t)row0 * K;
    for (int i = tid * 4; i < 32 * K; i += 256 * 4)
        *reinterpret_cast<float4*>(&Xs[i]) = *reinterpret_cast<const float4*>(&Xbase[i]);
    __syncthreads();

    int wid = tid >> 6, lane = tid & 63;
    int rbase = wid * 8;
    float acc[8];
#pragma unroll
    for (int r = 0; r < 8; ++r) acc[r] = 0.f;

    for (int k4 = 0; k4 < K / 4; ++k4) {
        float w0 = Ws[(k4 * 4 + 0) * 64 + lane];
        float w1 = Ws[(k4 * 4 + 1) * 64 + lane];
        float w2 = Ws[(k4 * 4 + 2) * 64 + lane];
        float w3 = Ws[(k4 * 4 + 3) * 64 + lane];
#pragma unroll
        for (int r = 0; r < 8; ++r) {
            float4 xv = *reinterpret_cast<const float4*>(&Xs[(rbase + r) * K + k4 * 4]);
            acc[r] += xv.x * w0 + xv.y * w1 + xv.z * w2 + xv.w * w3;
        }
    }
#pragma unroll
    for (int r = 0; r < 8; ++r) {
        int row = row0 + rbase + r;
        U[(size_t)row * 64 + lane] = acc[r] * rs[row];
    }
}

// ---------- aggregation: wave = node, 16 lanes x 4 edges, float4 gathers ----------
template <bool RELU>
__global__ __launch_bounds__(256) void agg_kernel(const float* __restrict__ u,
                                                  const int* __restrict__ off,
                                                  const int* __restrict__ col,
                                                  const float* __restrict__ dinv,
                                                  const float* __restrict__ bias,
                                                  float* __restrict__ H, int n) {
    int wid = threadIdx.x >> 6, lane = threadIdx.x & 63;
    int node = blockIdx.x * 4 + wid;
    if (node >= n) return;
    int r = lane >> 4, c = lane & 15;
    int beg = off[node], end = off[node + 1];
    float4 acc = make_float4(0.f, 0.f, 0.f, 0.f);
    for (int e = beg + r; e < end; e += 4) {
        int s = col[e];
        float4 v = *reinterpret_cast<const float4*>(&u[(size_t)s * 64 + c * 4]);
        acc.x += v.x; acc.y += v.y; acc.z += v.z; acc.w += v.w;
    }
#pragma unroll
    for (int m = 16; m <= 32; m <<= 1) {
        acc.x += __shfl_xor(acc.x, m);
        acc.y += __shfl_xor(acc.y, m);
        acc.z += __shfl_xor(acc.z, m);
        acc.w += __shfl_xor(acc.w, m);
    }
    if (r == 0) {
        float4 self = *reinterpret_cast<const float4*>(&u[(size_t)node * 64 + c * 4]);
        float di = dinv[node];
        float4 b4 = *reinterpret_cast<const float4*>(&bias[c * 4]);
        float4 o;
        o.x = di * (acc.x + self.x) + b4.x;
        o.y = di * (acc.y + self.y) + b4.y;
        o.z = di * (acc.z + self.z) + b4.z;
        o.w = di * (acc.w + self.w) + b4.w;
        if (RELU) {
            o.x = fmaxf(o.x, 0.f); o.y = fmaxf(o.y, 0.f);
            o.z = fmaxf(o.z, 0.f); o.w = fmaxf(o.w, 0.f);
        }
        *reinterpret_cast<float4*>(&H[(size_t)node * 64 + c * 4]) = o;
    }
}

// ---------- pooling: sorted batch, segmented wave reduction ----------
__global__ __launch_bounds__(256) void pool_kernel(const float* __restrict__ H,
                                                   const int* __restrict__ batch,
                                                   float* __restrict__ pooled,
                                                   int* __restrict__ cntg,
                                                   int n, int chunk) {
    int wid_g = blockIdx.x * 4 + (threadIdx.x >> 6);
    int lane = threadIdx.x & 63;
    int start = wid_g * chunk;
    if (start >= n) return;
    int end = min(n, start + chunk);
    int g_cur = batch[start];
    float acc = 0.f;
    int c_loc = 0;
    for (int i = start; i < end; ++i) {
        int g = batch[i];
        if (g != g_cur) {
            atomicAdd(&pooled[g_cur * 64 + lane], acc);
            if (lane == 0) atomicAdd(&cntg[g_cur], c_loc);
            acc = 0.f; c_loc = 0; g_cur = g;
        }
        acc += H[(size_t)i * 64 + lane];
        c_loc++;
    }
    atomicAdd(&pooled[g_cur * 64 + lane], acc);
    if (lane == 0) atomicAdd(&cntg[g_cur], c_loc);
}

// ---------- head: mean, folded MLP, softmax over graphs ----------
__global__ __launch_bounds__(512) void head_kernel(const float* __restrict__ pooled,
                                                   const int* __restrict__ cntg,
                                                   const float* __restrict__ Wl1,
                                                   const float* __restrict__ bl1,
                                                   const float* __restrict__ Wl2,
                                                   const float* __restrict__ bl2,
                                                   float* __restrict__ out) {
    __shared__ float Weff[64 * 2];
    __shared__ float beff[2];
    __shared__ float red[512];
    int tid = threadIdx.x;
    if (tid < 128) {
        int c = tid >> 1, j = tid & 1;
        float s = 0.f;
        for (int k = 0; k < 32; ++k) s += Wl1[c * 32 + k] * Wl2[k * 2 + j];
        Weff[c * 2 + j] = s;
    }
    if (tid < 2) {
        float s = bl2[tid];
        for (int k = 0; k < 32; ++k) s += bl1[k] * Wl2[k * 2 + tid];
        beff[tid] = s;
    }
    __syncthreads();

    int g = tid;
    float cn = fmaxf((float)cntg[g], 1.f);
    float z0 = beff[0], z1 = beff[1];
    for (int c = 0; c < 64; ++c) {
        float p = pooled[g * 64 + c] / cn;
        z0 += p * Weff[c * 2 + 0];
        z1 += p * Weff[c * 2 + 1];
    }

    red[tid] = z0; __syncthreads();
    for (int s = 256; s > 0; s >>= 1) { if (tid < s) red[tid] = fmaxf(red[tid], red[tid + s]); __syncthreads(); }
    float m0 = red[0]; __syncthreads();
    float e0 = expf(z0 - m0);
    red[tid] = e0; __syncthreads();
    for (int s = 256; s > 0; s >>= 1) { if (tid < s) red[tid] += red[tid + s]; __syncthreads(); }
    float s0 = red[0]; __syncthreads();
    out[g * 2 + 0] = e0 / s0;

    red[tid] = z1; __syncthreads();
    for (int s = 256; s > 0; s >>= 1) { if (tid < s) red[tid] = fmaxf(red[tid], red[tid + s]); __syncthreads(); }
    float m1 = red[0]; __syncthreads();
    float e1 = expf(z1 - m1);
    red[tid] = e1; __syncthreads();
    for (int s = 256; s > 0; s >>= 1) { if (tid < s) red[tid] += red[tid + s]; __syncthreads(); }
    float s1 = red[0]; __syncthreads();
    out[g * 2 + 1] = e1 / s1;
}

// ---------- launch ----------
extern "C" void kernel_launch(void* const* d_in, const int* in_sizes, int n_in,
                              void* d_out, int out_size, void* d_ws, size_t ws_size,
                              hipStream_t stream) {
    const float* x   = (const float*)d_in[0];
    const int*   ei  = (const int*)d_in[1];
    const int*   bat = (const int*)d_in[2];
    const float* W1  = (const float*)d_in[3];
    const float* b1  = (const float*)d_in[4];
    const float* W2  = (const float*)d_in[5];
    const float* b2  = (const float*)d_in[6];
    const float* Wl1 = (const float*)d_in[7];
    const float* bl1 = (const float*)d_in[8];
    const float* Wl2 = (const float*)d_in[9];
    const float* bl2 = (const float*)d_in[10];
    float* out = (float*)d_out;

    const int N = N_NODES, E = N_EDGES;
    const int* src = ei;
    const int* dst = ei + E;

    size_t o = 0;
    auto alloc = [&](size_t bytes) {
        void* p = (char*)d_ws + o;
        o += (bytes + 255) / 256 * 256;
        return p;
    };
    int*   bcnt   = (int*)alloc((size_t)(NB + 1) * 4);
    int*   bbase  = (int*)alloc((size_t)(NB + 1) * 4);
    int*   cursor = (int*)alloc((size_t)NB * 4);
    int*   off    = (int*)alloc((size_t)(N + 1) * 4);
    float* dinv   = (float*)alloc((size_t)N * 4);
    int2*  pairs  = (int2*)alloc((size_t)E * 8);
    int*   col    = (int*)alloc((size_t)E * 4);
    float* T      = (float*)alloc((size_t)N * 64 * 4);
    float* H      = (float*)alloc((size_t)N * 64 * 4);
    float* pooled = (float*)alloc((size_t)N_GRAPHS * 64 * 4);
    int*   cntg   = (int*)alloc((size_t)N_GRAPHS * 4);

    // per-call zeroing of atomic targets (ws is not re-poisoned between replays)
    hipMemsetAsync(bcnt, 0, (size_t)(NB + 1) * 4, stream);
    hipMemsetAsync(pooled, 0, (size_t)N_GRAPHS * 64 * 4, stream);
    hipMemsetAsync(cntg, 0, (size_t)N_GRAPHS * 4, stream);

    // CSR build: bucket histogram -> scan -> bucketed scatter -> per-bucket sort
    int ablocks = (E + A_TILE - 1) / A_TILE;
    bhist_kernel<<<ablocks, 256, 0, stream>>>(dst, bcnt, E);
    bscan_kernel<<<1, 512, 0, stream>>>(bcnt, bbase, cursor, off + N, E);
    scatter_kernel<<<ablocks, 256, 0, stream>>>(src, dst, cursor, pairs, E);
    bucket_kernel<<<NB, 256, 0, stream>>>(pairs, bbase, col, off, dinv, N);

    // layer 1: U = dinv * (x @ W1) ; H = relu(dinv * (sum + self) + b1)
    lin_kernel<128><<<N / 32, 256, 0, stream>>>(x, W1, dinv, T);
    agg_kernel<true><<<(N + 3) / 4, 256, 0, stream>>>(T, off, col, dinv, b1, H, N);

    // layer 2
    lin_kernel<64><<<N / 32, 256, 0, stream>>>(H, W2, dinv, T);
    agg_kernel<false><<<(N + 3) / 4, 256, 0, stream>>>(T, off, col, dinv, b2, H, N);

    // pooling
    int chunk = (N + 511) / 512;
    pool_kernel<<<128, 256, 0, stream>>>(H, bat, pooled, cntg, N, chunk);

    // head + softmax over graphs
    head_kernel<<<1, 512, 0, stream>>>(pooled, cntg, Wl1, bl1, Wl2, bl2, out);
}

// Round 3
// 419.743 us; speedup vs baseline: 2.6363x; 1.2782x over previous
//
#include <hip/hip_runtime.h>
#include <hip/hip_fp16.h>
#include <math.h>

#define N_NODES 100000
#define N_EDGES 3200000
#define N_GRAPHS 512

#define BSHIFT 8
#define BSPAN 256                      // nodes per bucket
#define NB 391                         // ceil(N_NODES / BSPAN)
#define A_ITEMS 8
#define A_TILE (A_ITEMS * 256)         // edges per scatter block

// ---------- pass A1: global bucket histogram ----------
__global__ __launch_bounds__(256) void bhist_kernel(const int* __restrict__ dst,
                                                    int* __restrict__ bcnt, int E) {
    __shared__ int h[NB];
    int tid = threadIdx.x;
    for (int b = tid; b < NB; b += 256) h[b] = 0;
    __syncthreads();
    int base = blockIdx.x * A_TILE;
    for (int i = 0; i < A_ITEMS; ++i) {
        int e = base + i * 256 + tid;
        if (e < E) atomicAdd(&h[dst[e] >> BSHIFT], 1);
    }
    __syncthreads();
    for (int b = tid; b < NB; b += 256)
        if (h[b]) atomicAdd(&bcnt[b], h[b]);
}

// ---------- pass A1.5: scan buckets -> bases + cursors ----------
__global__ __launch_bounds__(512) void bscan_kernel(const int* __restrict__ bcnt,
                                                    int* __restrict__ bbase,
                                                    int* __restrict__ cursor,
                                                    int* __restrict__ offN, int E) {
    __shared__ int s[512];
    int tid = threadIdx.x;
    int v = (tid < NB) ? bcnt[tid] : 0;
    s[tid] = v;
    __syncthreads();
    for (int st = 1; st < 512; st <<= 1) {
        int t = (tid >= st) ? s[tid - st] : 0;
        __syncthreads();
        s[tid] += t;
        __syncthreads();
    }
    int excl = s[tid] - v;
    if (tid < NB) { bbase[tid] = excl; cursor[tid] = excl; }
    if (tid == NB - 1) bbase[NB] = excl + v;
    if (tid == 0) *offN = E;
}

// ---------- pass A2: scatter edges into bucket segments (packed 32-bit) ----------
__global__ __launch_bounds__(256) void scatter_kernel(const int* __restrict__ src,
                                                      const int* __restrict__ dst,
                                                      int* __restrict__ cursor,
                                                      unsigned int* __restrict__ pairs, int E) {
    __shared__ int hcnt[NB];
    __shared__ int hbase[NB];
    int tid = threadIdx.x;
    for (int b = tid; b < NB; b += 256) hcnt[b] = 0;
    __syncthreads();
    int base = blockIdx.x * A_TILE;
    int sv[A_ITEMS], dv[A_ITEMS], rk[A_ITEMS];
    for (int i = 0; i < A_ITEMS; ++i) {
        int e = base + i * 256 + tid;
        if (e < E) {
            sv[i] = src[e];
            dv[i] = dst[e];
            rk[i] = atomicAdd(&hcnt[dv[i] >> BSHIFT], 1);
        } else dv[i] = -1;
    }
    __syncthreads();
    for (int b = tid; b < NB; b += 256) {
        int c = hcnt[b];
        if (c) hbase[b] = atomicAdd(&cursor[b], c);
    }
    __syncthreads();
    for (int i = 0; i < A_ITEMS; ++i) {
        if (dv[i] >= 0) {
            int b = dv[i] >> BSHIFT;
            pairs[hbase[b] + rk[i]] =
                ((unsigned int)sv[i] << BSHIFT) | (unsigned int)(dv[i] & (BSPAN - 1));
        }
    }
}

// ---------- pass B: per-bucket fine sort -> col, off, dinv ----------
__global__ __launch_bounds__(256) void bucket_kernel(const unsigned int* __restrict__ pairs,
                                                     const int* __restrict__ bbase,
                                                     int* __restrict__ col,
                                                     int* __restrict__ off,
                                                     float* __restrict__ dinv, int N) {
    __shared__ int ncnt[BSPAN];
    __shared__ int nbase[BSPAN];
    __shared__ int a[BSPAN];
    int b = blockIdx.x, tid = threadIdx.x;
    int base = bbase[b];
    int cntb = bbase[b + 1] - base;
    int n0 = b << BSHIFT;
    int nn = min(BSPAN, N - n0);
    ncnt[tid] = 0;
    __syncthreads();
    for (int i = tid; i < cntb; i += 256)
        atomicAdd(&ncnt[pairs[base + i] & (BSPAN - 1)], 1);
    __syncthreads();
    int v = ncnt[tid];
    a[tid] = v;
    __syncthreads();
    for (int st = 1; st < 256; st <<= 1) {
        int t = (tid >= st) ? a[tid - st] : 0;
        __syncthreads();
        a[tid] += t;
        __syncthreads();
    }
    nbase[tid] = a[tid] - v;
    if (tid < nn) {
        off[n0 + tid] = base + nbase[tid];
        dinv[n0 + tid] = rsqrtf((float)(v + 1));   // +1 self loop
    }
    ncnt[tid] = 0;   // reuse as cursor
    __syncthreads();
    for (int i = tid; i < cntb; i += 256) {
        unsigned int p = pairs[base + i];
        int dl = p & (BSPAN - 1);
        int pos = base + nbase[dl] + atomicAdd(&ncnt[dl], 1);
        col[pos] = (int)(p >> BSHIFT);
    }
}

// ---------- dense linear: U[n,64] = half(dinv[n] * (X[n,K] @ W[K,64])) ----------
template <int K>
__global__ __launch_bounds__(256) void lin_kernel(const float* __restrict__ X,
                                                  const float* __restrict__ W,
                                                  const float* __restrict__ rs,
                                                  __half* __restrict__ U) {
    __shared__ float Ws[K * 64];
    __shared__ float Xs[32 * K];
    int tid = threadIdx.x;
    for (int i = tid * 4; i < K * 64; i += 256 * 4)
        *reinterpret_cast<float4*>(&Ws[i]) = *reinterpret_cast<const float4*>(&W[i]);
    int row0 = blockIdx.x * 32;
    const float* Xbase = X + (size_t)row0 * K;
    for (int i = tid * 4; i < 32 * K; i += 256 * 4)
        *reinterpret_cast<float4*>(&Xs[i]) = *reinterpret_cast<const float4*>(&Xbase[i]);
    __syncthreads();

    int wid = tid >> 6, lane = tid & 63;
    int rbase = wid * 8;
    float acc[8];
#pragma unroll
    for (int r = 0; r < 8; ++r) acc[r] = 0.f;

    for (int k4 = 0; k4 < K / 4; ++k4) {
        float w0 = Ws[(k4 * 4 + 0) * 64 + lane];
        float w1 = Ws[(k4 * 4 + 1) * 64 + lane];
        float w2 = Ws[(k4 * 4 + 2) * 64 + lane];
        float w3 = Ws[(k4 * 4 + 3) * 64 + lane];
#pragma unroll
        for (int r = 0; r < 8; ++r) {
            float4 xv = *reinterpret_cast<const float4*>(&Xs[(rbase + r) * K + k4 * 4]);
            acc[r] += xv.x * w0 + xv.y * w1 + xv.z * w2 + xv.w * w3;
        }
    }
#pragma unroll
    for (int r = 0; r < 8; ++r) {
        int row = row0 + rbase + r;
        U[(size_t)row * 64 + lane] = __float2half(acc[r] * rs[row]);
    }
}

// ---------- aggregation: wave = node, 8 lanes/edge x 8 edges, 16B fp16 gathers ----------
template <bool RELU>
__global__ __launch_bounds__(256) void agg_kernel(const __half* __restrict__ u,
                                                  const int* __restrict__ off,
                                                  const int* __restrict__ col,
                                                  const float* __restrict__ dinv,
                                                  const float* __restrict__ bias,
                                                  float* __restrict__ H, int n) {
    int wid = threadIdx.x >> 6, lane = threadIdx.x & 63;
    int node = blockIdx.x * 4 + wid;
    if (node >= n) return;
    int r = lane >> 3, c = lane & 7;   // edge slot, feat group (8 feats of 64)
    int beg = off[node], end = off[node + 1];
    float acc[8];
#pragma unroll
    for (int j = 0; j < 8; ++j) acc[j] = 0.f;

    union Pk { float4 f; __half2 h[4]; };
    int e = beg + r;
    while (e + 8 < end) {
        int s0 = col[e], s1 = col[e + 8];
        Pk a0, a1;
        a0.f = *reinterpret_cast<const float4*>(&u[(size_t)s0 * 64 + c * 8]);
        a1.f = *reinterpret_cast<const float4*>(&u[(size_t)s1 * 64 + c * 8]);
#pragma unroll
        for (int j = 0; j < 4; ++j) {
            float2 t0 = __half22float2(a0.h[j]);
            float2 t1 = __half22float2(a1.h[j]);
            acc[2 * j]     += t0.x + t1.x;
            acc[2 * j + 1] += t0.y + t1.y;
        }
        e += 16;
    }
    if (e < end) {
        int s = col[e];
        Pk a0;
        a0.f = *reinterpret_cast<const float4*>(&u[(size_t)s * 64 + c * 8]);
#pragma unroll
        for (int j = 0; j < 4; ++j) {
            float2 t0 = __half22float2(a0.h[j]);
            acc[2 * j]     += t0.x;
            acc[2 * j + 1] += t0.y;
        }
    }
#pragma unroll
    for (int m = 8; m <= 32; m <<= 1) {
#pragma unroll
        for (int j = 0; j < 8; ++j) acc[j] += __shfl_xor(acc[j], m);
    }
    if (r == 0) {
        Pk sf;
        sf.f = *reinterpret_cast<const float4*>(&u[(size_t)node * 64 + c * 8]);
        float di = dinv[node];
        float4 b0 = *reinterpret_cast<const float4*>(&bias[c * 8]);
        float4 b1 = *reinterpret_cast<const float4*>(&bias[c * 8 + 4]);
        float o[8];
#pragma unroll
        for (int j = 0; j < 4; ++j) {
            float2 t = __half22float2(sf.h[j]);
            o[2 * j]     = di * (acc[2 * j]     + t.x);
            o[2 * j + 1] = di * (acc[2 * j + 1] + t.y);
        }
        o[0] += b0.x; o[1] += b0.y; o[2] += b0.z; o[3] += b0.w;
        o[4] += b1.x; o[5] += b1.y; o[6] += b1.z; o[7] += b1.w;
        if (RELU) {
#pragma unroll
            for (int j = 0; j < 8; ++j) o[j] = fmaxf(o[j], 0.f);
        }
        float4 w0 = make_float4(o[0], o[1], o[2], o[3]);
        float4 w1 = make_float4(o[4], o[5], o[6], o[7]);
        *reinterpret_cast<float4*>(&H[(size_t)node * 64 + c * 8])     = w0;
        *reinterpret_cast<float4*>(&H[(size_t)node * 64 + c * 8 + 4]) = w1;
    }
}

// ---------- pooling: sorted batch, segmented wave reduction ----------
__global__ __launch_bounds__(256) void pool_kernel(const float* __restrict__ H,
                                                   const int* __restrict__ batch,
                                                   float* __restrict__ pooled,
                                                   int* __restrict__ cntg,
                                                   int n, int chunk) {
    int wid_g = blockIdx.x * 4 + (threadIdx.x >> 6);
    int lane = threadIdx.x & 63;
    int start = wid_g * chunk;
    if (start >= n) return;
    int end = min(n, start + chunk);
    int g_cur = batch[start];
    float acc = 0.f;
    int c_loc = 0;
    for (int i = start; i < end; ++i) {
        int g = batch[i];
        if (g != g_cur) {
            atomicAdd(&pooled[g_cur * 64 + lane], acc);
            if (lane == 0) atomicAdd(&cntg[g_cur], c_loc);
            acc = 0.f; c_loc = 0; g_cur = g;
        }
        acc += H[(size_t)i * 64 + lane];
        c_loc++;
    }
    atomicAdd(&pooled[g_cur * 64 + lane], acc);
    if (lane == 0) atomicAdd(&cntg[g_cur], c_loc);
}

// ---------- head: mean, folded MLP, softmax over graphs ----------
__global__ __launch_bounds__(512) void head_kernel(const float* __restrict__ pooled,
                                                   const int* __restrict__ cntg,
                                                   const float* __restrict__ Wl1,
                                                   const float* __restrict__ bl1,
                                                   const float* __restrict__ Wl2,
                                                   const float* __restrict__ bl2,
                                                   float* __restrict__ out) {
    __shared__ float Weff[64 * 2];
    __shared__ float beff[2];
    __shared__ float red[512];
    int tid = threadIdx.x;
    if (tid < 128) {
        int c = tid >> 1, j = tid & 1;
        float s = 0.f;
        for (int k = 0; k < 32; ++k) s += Wl1[c * 32 + k] * Wl2[k * 2 + j];
        Weff[c * 2 + j] = s;
    }
    if (tid < 2) {
        float s = bl2[tid];
        for (int k = 0; k < 32; ++k) s += bl1[k] * Wl2[k * 2 + tid];
        beff[tid] = s;
    }
    __syncthreads();

    int g = tid;
    float cn = fmaxf((float)cntg[g], 1.f);
    float z0 = beff[0], z1 = beff[1];
    for (int c = 0; c < 64; ++c) {
        float p = pooled[g * 64 + c] / cn;
        z0 += p * Weff[c * 2 + 0];
        z1 += p * Weff[c * 2 + 1];
    }

    red[tid] = z0; __syncthreads();
    for (int s = 256; s > 0; s >>= 1) { if (tid < s) red[tid] = fmaxf(red[tid], red[tid + s]); __syncthreads(); }
    float m0 = red[0]; __syncthreads();
    float e0 = expf(z0 - m0);
    red[tid] = e0; __syncthreads();
    for (int s = 256; s > 0; s >>= 1) { if (tid < s) red[tid] += red[tid + s]; __syncthreads(); }
    float s0 = red[0]; __syncthreads();
    out[g * 2 + 0] = e0 / s0;

    red[tid] = z1; __syncthreads();
    for (int s = 256; s > 0; s >>= 1) { if (tid < s) red[tid] = fmaxf(red[tid], red[tid + s]); __syncthreads(); }
    float m1 = red[0]; __syncthreads();
    float e1 = expf(z1 - m1);
    red[tid] = e1; __syncthreads();
    for (int s = 256; s > 0; s >>= 1) { if (tid < s) red[tid] += red[tid + s]; __syncthreads(); }
    float s1 = red[0]; __syncthreads();
    out[g * 2 + 1] = e1 / s1;
}

// ---------- launch ----------
extern "C" void kernel_launch(void* const* d_in, const int* in_sizes, int n_in,
                              void* d_out, int out_size, void* d_ws, size_t ws_size,
                              hipStream_t stream) {
    const float* x   = (const float*)d_in[0];
    const int*   ei  = (const int*)d_in[1];
    const int*   bat = (const int*)d_in[2];
    const float* W1  = (const float*)d_in[3];
    const float* b1  = (const float*)d_in[4];
    const float* W2  = (const float*)d_in[5];
    const float* b2  = (const float*)d_in[6];
    const float* Wl1 = (const float*)d_in[7];
    const float* bl1 = (const float*)d_in[8];
    const float* Wl2 = (const float*)d_in[9];
    const float* bl2 = (const float*)d_in[10];
    float* out = (float*)d_out;

    const int N = N_NODES, E = N_EDGES;
    const int* src = ei;
    const int* dst = ei + E;

    size_t o = 0;
    auto alloc = [&](size_t bytes) {
        void* p = (char*)d_ws + o;
        o += (bytes + 255) / 256 * 256;
        return p;
    };
    int*          bcnt   = (int*)alloc((size_t)(NB + 1) * 4);
    int*          bbase  = (int*)alloc((size_t)(NB + 1) * 4);
    int*          cursor = (int*)alloc((size_t)NB * 4);
    int*          off    = (int*)alloc((size_t)(N + 1) * 4);
    float*        dinv   = (float*)alloc((size_t)N * 4);
    unsigned int* pairs  = (unsigned int*)alloc((size_t)E * 4);
    int*          col    = (int*)alloc((size_t)E * 4);
    __half*       T      = (__half*)alloc((size_t)N * 64 * 2);
    float*        H      = (float*)alloc((size_t)N * 64 * 4);
    float*        pooled = (float*)alloc((size_t)N_GRAPHS * 64 * 4);
    int*          cntg   = (int*)alloc((size_t)N_GRAPHS * 4);

    // per-call zeroing of atomic targets (ws is not re-poisoned between replays)
    hipMemsetAsync(bcnt, 0, (size_t)(NB + 1) * 4, stream);
    hipMemsetAsync(pooled, 0, (size_t)N_GRAPHS * 64 * 4, stream);
    hipMemsetAsync(cntg, 0, (size_t)N_GRAPHS * 4, stream);

    // CSR build: bucket histogram -> scan -> bucketed scatter -> per-bucket sort
    int ablocks = (E + A_TILE - 1) / A_TILE;
    bhist_kernel<<<ablocks, 256, 0, stream>>>(dst, bcnt, E);
    bscan_kernel<<<1, 512, 0, stream>>>(bcnt, bbase, cursor, off + N, E);
    scatter_kernel<<<ablocks, 256, 0, stream>>>(src, dst, cursor, pairs, E);
    bucket_kernel<<<NB, 256, 0, stream>>>(pairs, bbase, col, off, dinv, N);

    // layer 1: U = half(dinv * (x @ W1)) ; H = relu(dinv * (sum + self) + b1)
    lin_kernel<128><<<N / 32, 256, 0, stream>>>(x, W1, dinv, T);
    agg_kernel<true><<<(N + 3) / 4, 256, 0, stream>>>(T, off, col, dinv, b1, H, N);

    // layer 2
    lin_kernel<64><<<N / 32, 256, 0, stream>>>(H, W2, dinv, T);
    agg_kernel<false><<<(N + 3) / 4, 256, 0, stream>>>(T, off, col, dinv, b2, H, N);

    // pooling
    int chunk = (N + 511) / 512;
    pool_kernel<<<128, 256, 0, stream>>>(H, bat, pooled, cntg, N, chunk);

    // head + softmax over graphs
    head_kernel<<<1, 512, 0, stream>>>(pooled, cntg, Wl1, bl1, Wl2, bl2, out);
}

// Round 4
// 322.543 us; speedup vs baseline: 3.4307x; 1.3014x over previous
//
#include <hip/hip_runtime.h>
#include <hip/hip_fp16.h>
#include <math.h>

#define N_NODES 100000
#define N_EDGES 3200000
#define N_GRAPHS 512

#define BSHIFT 8
#define BSPAN 256                      // nodes per bucket
#define NB 391                         // ceil(N_NODES / BSPAN)
#define SBLK 16384                     // edges per scatter block
#define SBLOCKS ((N_EDGES + SBLK - 1) / SBLK)   // 196

// ---------- pass 1: per-block bucket histogram -> pcnt[block][bucket] ----------
__global__ __launch_bounds__(256) void phist_kernel(const int* __restrict__ dst,
                                                    int* __restrict__ pcnt, int E) {
    __shared__ int h[NB];
    int tid = threadIdx.x;
    for (int b = tid; b < NB; b += 256) h[b] = 0;
    __syncthreads();
    int base = blockIdx.x * SBLK;
    int end = min(E, base + SBLK);
    for (int e = base + tid; e < end; e += 256)
        atomicAdd(&h[dst[e] >> BSHIFT], 1);
    __syncthreads();
    int* row = pcnt + (size_t)blockIdx.x * NB;
    for (int b = tid; b < NB; b += 256) row[b] = h[b];
}

// ---------- pass 2: scan -> bucket bases + per-block bases (in-place on pcnt) ----------
__global__ __launch_bounds__(512) void pscan_kernel(int* __restrict__ pcnt,
                                                    int* __restrict__ bbase,
                                                    int* __restrict__ offN, int E) {
    __shared__ int s[512];
    int tid = threadIdx.x;
    int tot = 0;
    if (tid < NB)
        for (int blk = 0; blk < SBLOCKS; ++blk) tot += pcnt[(size_t)blk * NB + tid];
    s[tid] = tot;
    __syncthreads();
    for (int st = 1; st < 512; st <<= 1) {
        int t = (tid >= st) ? s[tid - st] : 0;
        __syncthreads();
        s[tid] += t;
        __syncthreads();
    }
    int excl = s[tid] - tot;
    if (tid < NB) {
        bbase[tid] = excl;
        int run = excl;
        for (int blk = 0; blk < SBLOCKS; ++blk) {
            size_t idx = (size_t)blk * NB + tid;
            int c = pcnt[idx];
            pcnt[idx] = run;
            run += c;
        }
    }
    if (tid == NB - 1) bbase[NB] = excl + tot;
    if (tid == 0) *offN = E;
}

// ---------- pass 3: scatter edges into bucket segments (packed 32-bit) ----------
__global__ __launch_bounds__(256) void scatter2_kernel(const int* __restrict__ src,
                                                       const int* __restrict__ dst,
                                                       const int* __restrict__ pbase,
                                                       unsigned int* __restrict__ pairs, int E) {
    __shared__ int hrank[NB];
    __shared__ int hb[NB];
    int tid = threadIdx.x;
    const int* row = pbase + (size_t)blockIdx.x * NB;
    for (int b = tid; b < NB; b += 256) { hrank[b] = 0; hb[b] = row[b]; }
    __syncthreads();
    int base = blockIdx.x * SBLK;
    int end = min(E, base + SBLK);
    for (int e = base + tid; e < end; e += 256) {
        int d = dst[e];
        int b = d >> BSHIFT;
        int rk = atomicAdd(&hrank[b], 1);
        pairs[hb[b] + rk] = ((unsigned int)src[e] << BSHIFT) | (unsigned int)(d & (BSPAN - 1));
    }
}

// ---------- pass 4: per-bucket fine sort -> col, off, dinv ----------
__global__ __launch_bounds__(256) void bucket_kernel(const unsigned int* __restrict__ pairs,
                                                     const int* __restrict__ bbase,
                                                     int* __restrict__ col,
                                                     int* __restrict__ off,
                                                     float* __restrict__ dinv, int N) {
    __shared__ int ncnt[BSPAN];
    __shared__ int nbase[BSPAN];
    __shared__ int a[BSPAN];
    int b = blockIdx.x, tid = threadIdx.x;
    int base = bbase[b];
    int cntb = bbase[b + 1] - base;
    int n0 = b << BSHIFT;
    int nn = min(BSPAN, N - n0);
    ncnt[tid] = 0;
    __syncthreads();
    for (int i = tid; i < cntb; i += 256)
        atomicAdd(&ncnt[pairs[base + i] & (BSPAN - 1)], 1);
    __syncthreads();
    int v = ncnt[tid];
    a[tid] = v;
    __syncthreads();
    for (int st = 1; st < 256; st <<= 1) {
        int t = (tid >= st) ? a[tid - st] : 0;
        __syncthreads();
        a[tid] += t;
        __syncthreads();
    }
    nbase[tid] = a[tid] - v;
    if (tid < nn) {
        off[n0 + tid] = base + nbase[tid];
        dinv[n0 + tid] = rsqrtf((float)(v + 1));   // +1 self loop
    }
    ncnt[tid] = 0;   // reuse as cursor
    __syncthreads();
    for (int i = tid; i < cntb; i += 256) {
        unsigned int p = pairs[base + i];
        int dl = p & (BSPAN - 1);
        int pos = base + nbase[dl] + atomicAdd(&ncnt[dl], 1);
        col[pos] = (int)(p >> BSHIFT);
    }
}

// ---------- dense linear: U[n,64] = half(dinv[n] * (X[n,K] @ W[K,64])) ----------
template <int K>
__global__ __launch_bounds__(256) void lin_kernel(const float* __restrict__ X,
                                                  const float* __restrict__ W,
                                                  const float* __restrict__ rs,
                                                  __half* __restrict__ U) {
    __shared__ float Ws[K * 64];
    __shared__ float Xs[32 * K];
    int tid = threadIdx.x;
    for (int i = tid * 4; i < K * 64; i += 256 * 4)
        *reinterpret_cast<float4*>(&Ws[i]) = *reinterpret_cast<const float4*>(&W[i]);
    int row0 = blockIdx.x * 32;
    const float* Xbase = X + (size_t)row0 * K;
    for (int i = tid * 4; i < 32 * K; i += 256 * 4)
        *reinterpret_cast<float4*>(&Xs[i]) = *reinterpret_cast<const float4*>(&Xbase[i]);
    __syncthreads();

    int wid = tid >> 6, lane = tid & 63;
    int rbase = wid * 8;
    float acc[8];
#pragma unroll
    for (int r = 0; r < 8; ++r) acc[r] = 0.f;

    for (int k4 = 0; k4 < K / 4; ++k4) {
        float w0 = Ws[(k4 * 4 + 0) * 64 + lane];
        float w1 = Ws[(k4 * 4 + 1) * 64 + lane];
        float w2 = Ws[(k4 * 4 + 2) * 64 + lane];
        float w3 = Ws[(k4 * 4 + 3) * 64 + lane];
#pragma unroll
        for (int r = 0; r < 8; ++r) {
            float4 xv = *reinterpret_cast<const float4*>(&Xs[(rbase + r) * K + k4 * 4]);
            acc[r] += xv.x * w0 + xv.y * w1 + xv.z * w2 + xv.w * w3;
        }
    }
#pragma unroll
    for (int r = 0; r < 8; ++r) {
        int row = row0 + rbase + r;
        U[(size_t)row * 64 + lane] = __float2half(acc[r] * rs[row]);
    }
}

// ---------- aggregation: wave = node, 8 lanes/edge x 8 edges, 16B fp16 gathers.
// POOL=true: skip H write, block-accumulate into pooled[] (batch sorted). ----------
template <bool RELU, bool POOL>
__global__ __launch_bounds__(256) void agg_kernel(const __half* __restrict__ u,
                                                  const int* __restrict__ off,
                                                  const int* __restrict__ col,
                                                  const float* __restrict__ dinv,
                                                  const float* __restrict__ bias,
                                                  float* __restrict__ H,
                                                  float* __restrict__ pooled,
                                                  const int* __restrict__ batch, int n) {
    __shared__ float sh[4][64];
    __shared__ int sg[4];
    int wid = threadIdx.x >> 6, lane = threadIdx.x & 63;
    int node = blockIdx.x * 4 + wid;
    bool valid = node < n;
    if (!POOL && !valid) return;
    int r = lane >> 3, c = lane & 7;   // edge slot, feat group (8 feats of 64)
    float o[8];
#pragma unroll
    for (int j = 0; j < 8; ++j) o[j] = 0.f;

    if (valid) {
        int beg = off[node], end = off[node + 1];
        float acc[8];
#pragma unroll
        for (int j = 0; j < 8; ++j) acc[j] = 0.f;
        union Pk { float4 f; __half2 h[4]; };
        int e = beg + r;
        while (e + 8 < end) {
            int s0 = col[e], s1 = col[e + 8];
            Pk a0, a1;
            a0.f = *reinterpret_cast<const float4*>(&u[(size_t)s0 * 64 + c * 8]);
            a1.f = *reinterpret_cast<const float4*>(&u[(size_t)s1 * 64 + c * 8]);
#pragma unroll
            for (int j = 0; j < 4; ++j) {
                float2 t0 = __half22float2(a0.h[j]);
                float2 t1 = __half22float2(a1.h[j]);
                acc[2 * j]     += t0.x + t1.x;
                acc[2 * j + 1] += t0.y + t1.y;
            }
            e += 16;
        }
        if (e < end) {
            int s = col[e];
            Pk a0;
            a0.f = *reinterpret_cast<const float4*>(&u[(size_t)s * 64 + c * 8]);
#pragma unroll
            for (int j = 0; j < 4; ++j) {
                float2 t0 = __half22float2(a0.h[j]);
                acc[2 * j]     += t0.x;
                acc[2 * j + 1] += t0.y;
            }
        }
#pragma unroll
        for (int m = 8; m <= 32; m <<= 1) {
#pragma unroll
            for (int j = 0; j < 8; ++j) acc[j] += __shfl_xor(acc[j], m);
        }
        if (r == 0) {
            union Pk2 { float4 f; __half2 h[4]; } sf;
            sf.f = *reinterpret_cast<const float4*>(&u[(size_t)node * 64 + c * 8]);
            float di = dinv[node];
            float4 b0 = *reinterpret_cast<const float4*>(&bias[c * 8]);
            float4 b1 = *reinterpret_cast<const float4*>(&bias[c * 8 + 4]);
#pragma unroll
            for (int j = 0; j < 4; ++j) {
                float2 t = __half22float2(sf.h[j]);
                o[2 * j]     = di * (acc[2 * j]     + t.x);
                o[2 * j + 1] = di * (acc[2 * j + 1] + t.y);
            }
            o[0] += b0.x; o[1] += b0.y; o[2] += b0.z; o[3] += b0.w;
            o[4] += b1.x; o[5] += b1.y; o[6] += b1.z; o[7] += b1.w;
            if (RELU) {
#pragma unroll
                for (int j = 0; j < 8; ++j) o[j] = fmaxf(o[j], 0.f);
            }
        }
    }

    if (!POOL) {
        if (r == 0) {
            float4 w0 = make_float4(o[0], o[1], o[2], o[3]);
            float4 w1 = make_float4(o[4], o[5], o[6], o[7]);
            *reinterpret_cast<float4*>(&H[(size_t)node * 64 + c * 8])     = w0;
            *reinterpret_cast<float4*>(&H[(size_t)node * 64 + c * 8 + 4]) = w1;
        }
    } else {
        if (r == 0) {
#pragma unroll
            for (int j = 0; j < 8; ++j) sh[wid][c * 8 + j] = o[j];   // zeros if invalid
        }
        if (lane == 0) sg[wid] = valid ? batch[node] : -1;
        __syncthreads();
        if (threadIdx.x < 64) {
            float s = 0.f;
            int gp = -1;
            for (int w = 0; w < 4; ++w) {
                int g = sg[w];
                if (g < 0) continue;
                if (g != gp) {
                    if (gp >= 0) atomicAdd(&pooled[gp * 64 + threadIdx.x], s);
                    s = 0.f;
                    gp = g;
                }
                s += sh[w][threadIdx.x];
            }
            if (gp >= 0) atomicAdd(&pooled[gp * 64 + threadIdx.x], s);
        }
    }
}

// ---------- head: counts via binary search, mean, folded MLP, softmax over graphs ----------
__global__ __launch_bounds__(512) void head_kernel(const float* __restrict__ pooled,
                                                   const int* __restrict__ batch,
                                                   const float* __restrict__ Wl1,
                                                   const float* __restrict__ bl1,
                                                   const float* __restrict__ Wl2,
                                                   const float* __restrict__ bl2,
                                                   float* __restrict__ out, int N) {
    __shared__ float Weff[64 * 2];
    __shared__ float beff[2];
    __shared__ float red[512];
    int tid = threadIdx.x;
    if (tid < 128) {
        int c = tid >> 1, j = tid & 1;
        float s = 0.f;
        for (int k = 0; k < 32; ++k) s += Wl1[c * 32 + k] * Wl2[k * 2 + j];
        Weff[c * 2 + j] = s;
    }
    if (tid < 2) {
        float s = bl2[tid];
        for (int k = 0; k < 32; ++k) s += bl1[k] * Wl2[k * 2 + tid];
        beff[tid] = s;
    }
    __syncthreads();

    int g = tid;
    // count of nodes with batch == g via two lower_bounds on sorted batch
    auto lb = [&](int key) {
        int l = 0, r = N;
        while (l < r) { int m = (l + r) >> 1; if (batch[m] < key) l = m + 1; else r = m; }
        return l;
    };
    int cnt = lb(g + 1) - lb(g);
    float cn = fmaxf((float)cnt, 1.f);
    float z0 = beff[0], z1 = beff[1];
    for (int c = 0; c < 64; ++c) {
        float p = pooled[g * 64 + c] / cn;
        z0 += p * Weff[c * 2 + 0];
        z1 += p * Weff[c * 2 + 1];
    }

    red[tid] = z0; __syncthreads();
    for (int s = 256; s > 0; s >>= 1) { if (tid < s) red[tid] = fmaxf(red[tid], red[tid + s]); __syncthreads(); }
    float m0 = red[0]; __syncthreads();
    float e0 = expf(z0 - m0);
    red[tid] = e0; __syncthreads();
    for (int s = 256; s > 0; s >>= 1) { if (tid < s) red[tid] += red[tid + s]; __syncthreads(); }
    float s0 = red[0]; __syncthreads();
    out[g * 2 + 0] = e0 / s0;

    red[tid] = z1; __syncthreads();
    for (int s = 256; s > 0; s >>= 1) { if (tid < s) red[tid] = fmaxf(red[tid], red[tid + s]); __syncthreads(); }
    float m1 = red[0]; __syncthreads();
    float e1 = expf(z1 - m1);
    red[tid] = e1; __syncthreads();
    for (int s = 256; s > 0; s >>= 1) { if (tid < s) red[tid] += red[tid + s]; __syncthreads(); }
    float s1 = red[0]; __syncthreads();
    out[g * 2 + 1] = e1 / s1;
}

// ---------- launch ----------
extern "C" void kernel_launch(void* const* d_in, const int* in_sizes, int n_in,
                              void* d_out, int out_size, void* d_ws, size_t ws_size,
                              hipStream_t stream) {
    const float* x   = (const float*)d_in[0];
    const int*   ei  = (const int*)d_in[1];
    const int*   bat = (const int*)d_in[2];
    const float* W1  = (const float*)d_in[3];
    const float* b1  = (const float*)d_in[4];
    const float* W2  = (const float*)d_in[5];
    const float* b2  = (const float*)d_in[6];
    const float* Wl1 = (const float*)d_in[7];
    const float* bl1 = (const float*)d_in[8];
    const float* Wl2 = (const float*)d_in[9];
    const float* bl2 = (const float*)d_in[10];
    float* out = (float*)d_out;

    const int N = N_NODES, E = N_EDGES;
    const int* src = ei;
    const int* dst = ei + E;

    size_t o = 0;
    auto alloc = [&](size_t bytes) {
        void* p = (char*)d_ws + o;
        o += (bytes + 255) / 256 * 256;
        return p;
    };
    int*          pcnt   = (int*)alloc((size_t)SBLOCKS * NB * 4);
    int*          bbase  = (int*)alloc((size_t)(NB + 1) * 4);
    int*          off    = (int*)alloc((size_t)(N + 1) * 4);
    float*        dinv   = (float*)alloc((size_t)N * 4);
    unsigned int* pairs  = (unsigned int*)alloc((size_t)E * 4);
    int*          col    = (int*)alloc((size_t)E * 4);
    __half*       T      = (__half*)alloc((size_t)N * 64 * 2);
    float*        H      = (float*)alloc((size_t)N * 64 * 4);
    float*        pooled = (float*)alloc((size_t)N_GRAPHS * 64 * 4);

    // per-call zeroing of atomic targets (ws is not re-poisoned between replays)
    hipMemsetAsync(pooled, 0, (size_t)N_GRAPHS * 64 * 4, stream);

    // CSR build: per-block histogram -> scan -> scatter -> per-bucket sort
    phist_kernel<<<SBLOCKS, 256, 0, stream>>>(dst, pcnt, E);
    pscan_kernel<<<1, 512, 0, stream>>>(pcnt, bbase, off + N, E);
    scatter2_kernel<<<SBLOCKS, 256, 0, stream>>>(src, dst, pcnt, pairs, E);
    bucket_kernel<<<NB, 256, 0, stream>>>(pairs, bbase, col, off, dinv, N);

    // layer 1: U = half(dinv * (x @ W1)) ; H = relu(dinv * (sum + self) + b1)
    lin_kernel<128><<<N / 32, 256, 0, stream>>>(x, W1, dinv, T);
    agg_kernel<true, false><<<(N + 3) / 4, 256, 0, stream>>>(T, off, col, dinv, b1, H, nullptr, nullptr, N);

    // layer 2 (pooling fused into aggregation)
    lin_kernel<64><<<N / 32, 256, 0, stream>>>(H, W2, dinv, T);
    agg_kernel<false, true><<<(N + 3) / 4, 256, 0, stream>>>(T, off, col, dinv, b2, nullptr, pooled, bat, N);

    // head: counts + mean + folded MLP + softmax over graphs
    head_kernel<<<1, 512, 0, stream>>>(pooled, bat, Wl1, bl1, Wl2, bl2, out, N);
}

// Round 5
// 312.165 us; speedup vs baseline: 3.5448x; 1.0332x over previous
//
#include <hip/hip_runtime.h>
#include <hip/hip_fp16.h>
#include <math.h>

#define N_NODES 100000
#define N_EDGES 3200000
#define N_GRAPHS 512

#define BSHIFT 8
#define BSPAN 256                      // nodes per bucket
#define NB 391                         // ceil(N_NODES / BSPAN)
#define SBLK 16384                     // edges per scatter block
#define SBLOCKS ((N_EDGES + SBLK - 1) / SBLK)   // 196
#define PH 8                           // src phases for locality sort
#define PHSH 3
#define PSRC 14                        // src >> 14 -> 0..6 for N=100000

// ---------- pass 1: per-block bucket histogram -> pcnt[block][bucket] ----------
__global__ __launch_bounds__(256) void phist_kernel(const int* __restrict__ dst,
                                                    int* __restrict__ pcnt, int E) {
    __shared__ int h[NB];
    int tid = threadIdx.x;
    for (int b = tid; b < NB; b += 256) h[b] = 0;
    __syncthreads();
    int base = blockIdx.x * SBLK;
    int end = min(E, base + SBLK);
    for (int e = base + tid; e < end; e += 256)
        atomicAdd(&h[dst[e] >> BSHIFT], 1);
    __syncthreads();
    int* row = pcnt + (size_t)blockIdx.x * NB;
    for (int b = tid; b < NB; b += 256) row[b] = h[b];
}

// ---------- pass 2a: per-bucket scan over blocks (block b handles bucket b) ----------
__global__ __launch_bounds__(256) void pscanA_kernel(int* __restrict__ pcnt,
                                                     int* __restrict__ btot) {
    __shared__ int s[256];
    int b = blockIdx.x, tid = threadIdx.x;
    int v = (tid < SBLOCKS) ? pcnt[(size_t)tid * NB + b] : 0;
    s[tid] = v;
    __syncthreads();
    for (int st = 1; st < 256; st <<= 1) {
        int t = (tid >= st) ? s[tid - st] : 0;
        __syncthreads();
        s[tid] += t;
        __syncthreads();
    }
    int excl = s[tid] - v;
    if (tid < SBLOCKS) pcnt[(size_t)tid * NB + b] = excl;
    if (tid == SBLOCKS - 1) btot[b] = excl + v;
}

// ---------- pass 2b: scan bucket totals -> bbase ----------
__global__ __launch_bounds__(512) void pscanB_kernel(const int* __restrict__ btot,
                                                     int* __restrict__ bbase,
                                                     int* __restrict__ offN, int E) {
    __shared__ int s[512];
    int tid = threadIdx.x;
    int v = (tid < NB) ? btot[tid] : 0;
    s[tid] = v;
    __syncthreads();
    for (int st = 1; st < 512; st <<= 1) {
        int t = (tid >= st) ? s[tid - st] : 0;
        __syncthreads();
        s[tid] += t;
        __syncthreads();
    }
    int excl = s[tid] - v;
    if (tid < NB) bbase[tid] = excl;
    if (tid == NB - 1) bbase[NB] = excl + v;
    if (tid == 0) *offN = E;
}

// ---------- pass 3: scatter edges into bucket segments (packed 32-bit) ----------
__global__ __launch_bounds__(256) void scatter2_kernel(const int* __restrict__ src,
                                                       const int* __restrict__ dst,
                                                       const int* __restrict__ pbase,
                                                       const int* __restrict__ bbase,
                                                       unsigned int* __restrict__ pairs, int E) {
    __shared__ int hrank[NB];
    __shared__ int hb[NB];
    int tid = threadIdx.x;
    const int* row = pbase + (size_t)blockIdx.x * NB;
    for (int b = tid; b < NB; b += 256) { hrank[b] = 0; hb[b] = row[b] + bbase[b]; }
    __syncthreads();
    int base = blockIdx.x * SBLK;
    int end = min(E, base + SBLK);
    for (int e = base + tid; e < end; e += 256) {
        int d = dst[e];
        int b = d >> BSHIFT;
        int rk = atomicAdd(&hrank[b], 1);
        pairs[hb[b] + rk] = ((unsigned int)src[e] << BSHIFT) | (unsigned int)(d & (BSPAN - 1));
    }
}

// ---------- pass 4: per-bucket fine sort by (node, src-phase) -> col, off, dinv ----------
__global__ __launch_bounds__(256) void bucket_kernel(const unsigned int* __restrict__ pairs,
                                                     const int* __restrict__ bbase,
                                                     int* __restrict__ col,
                                                     int* __restrict__ off,
                                                     float* __restrict__ dinv, int N) {
    __shared__ int kcnt[BSPAN * PH];   // counts, then unused
    __shared__ int kcur[BSPAN * PH];   // cursors (exclusive bases)
    __shared__ int part[256];
    int b = blockIdx.x, tid = threadIdx.x;
    int base = bbase[b];
    int cntb = bbase[b + 1] - base;
    int n0 = b << BSHIFT;
    int nn = min(BSPAN, N - n0);
    for (int k = tid; k < BSPAN * PH; k += 256) kcnt[k] = 0;
    __syncthreads();
    for (int i = tid; i < cntb; i += 256) {
        unsigned int p = pairs[base + i];
        int dl = p & (BSPAN - 1);
        int s = (int)(p >> BSHIFT);
        atomicAdd(&kcnt[(dl << PHSH) | (s >> PSRC)], 1);
    }
    __syncthreads();
    // thread tid owns node dl=tid's 8 phase keys
    int loc[PH];
    int run = 0;
    int kb = tid * PH;
#pragma unroll
    for (int j = 0; j < PH; ++j) { loc[j] = kcnt[kb + j]; run += loc[j]; }
    part[tid] = run;
    __syncthreads();
    for (int st = 1; st < 256; st <<= 1) {
        int t = (tid >= st) ? part[tid - st] : 0;
        __syncthreads();
        part[tid] += t;
        __syncthreads();
    }
    int excl = part[tid] - run;
    int r2 = excl;
#pragma unroll
    for (int j = 0; j < PH; ++j) { kcur[kb + j] = r2; r2 += loc[j]; }
    if (tid < nn) {
        off[n0 + tid] = base + excl;
        dinv[n0 + tid] = rsqrtf((float)(run + 1));   // +1 self loop
    }
    __syncthreads();
    for (int i = tid; i < cntb; i += 256) {
        unsigned int p = pairs[base + i];
        int dl = p & (BSPAN - 1);
        int s = (int)(p >> BSHIFT);
        int k = (dl << PHSH) | (s >> PSRC);
        int pos = base + atomicAdd(&kcur[k], 1);
        col[pos] = s;
    }
}

// ---------- dense linear: U[n,64] = half(dinv[n] * (X[n,K] @ W[K,64])) ----------
template <int K>
__global__ __launch_bounds__(256) void lin_kernel(const float* __restrict__ X,
                                                  const float* __restrict__ W,
                                                  const float* __restrict__ rs,
                                                  __half* __restrict__ U) {
    __shared__ float Ws[K * 64];
    __shared__ float Xs[32 * K];
    int tid = threadIdx.x;
    for (int i = tid * 4; i < K * 64; i += 256 * 4)
        *reinterpret_cast<float4*>(&Ws[i]) = *reinterpret_cast<const float4*>(&W[i]);
    int row0 = blockIdx.x * 32;
    const float* Xbase = X + (size_t)row0 * K;
    for (int i = tid * 4; i < 32 * K; i += 256 * 4)
        *reinterpret_cast<float4*>(&Xs[i]) = *reinterpret_cast<const float4*>(&Xbase[i]);
    __syncthreads();

    int wid = tid >> 6, lane = tid & 63;
    int rbase = wid * 8;
    float acc[8];
#pragma unroll
    for (int r = 0; r < 8; ++r) acc[r] = 0.f;

    for (int k4 = 0; k4 < K / 4; ++k4) {
        float w0 = Ws[(k4 * 4 + 0) * 64 + lane];
        float w1 = Ws[(k4 * 4 + 1) * 64 + lane];
        float w2 = Ws[(k4 * 4 + 2) * 64 + lane];
        float w3 = Ws[(k4 * 4 + 3) * 64 + lane];
#pragma unroll
        for (int r = 0; r < 8; ++r) {
            float4 xv = *reinterpret_cast<const float4*>(&Xs[(rbase + r) * K + k4 * 4]);
            acc[r] += xv.x * w0 + xv.y * w1 + xv.z * w2 + xv.w * w3;
        }
    }
#pragma unroll
    for (int r = 0; r < 8; ++r) {
        int row = row0 + rbase + r;
        U[(size_t)row * 64 + lane] = __float2half(acc[r] * rs[row]);
    }
}

// ---------- aggregation: wave = node, 8 lanes/edge x 8 edges, fp16 pk accumulation.
// POOL=true: skip H write, block-accumulate into pooled[] (batch sorted). ----------
template <bool RELU, bool POOL>
__global__ __launch_bounds__(256) void agg_kernel(const __half* __restrict__ u,
                                                  const int* __restrict__ off,
                                                  const int* __restrict__ col,
                                                  const float* __restrict__ dinv,
                                                  const float* __restrict__ bias,
                                                  float* __restrict__ H,
                                                  float* __restrict__ pooled,
                                                  const int* __restrict__ batch, int n) {
    __shared__ float sh[4][64];
    __shared__ int sg[4];
    int wid = threadIdx.x >> 6, lane = threadIdx.x & 63;
    int node = blockIdx.x * 4 + wid;
    bool valid = node < n;
    if (!POOL && !valid) return;
    int r = lane >> 3, c = lane & 7;   // edge slot, feat group (8 feats of 64)
    float o[8];
#pragma unroll
    for (int j = 0; j < 8; ++j) o[j] = 0.f;

    if (valid) {
        int beg = off[node], end = off[node + 1];
        union Pk { float4 f; __half2 h[4]; };
        __half2 hacc[4];
#pragma unroll
        for (int j = 0; j < 4; ++j) hacc[j] = __float2half2_rn(0.f);
        int e = beg + r;
        while (e + 8 < end) {
            int s0 = col[e], s1 = col[e + 8];
            Pk a0, a1;
            a0.f = *reinterpret_cast<const float4*>(&u[(size_t)s0 * 64 + c * 8]);
            a1.f = *reinterpret_cast<const float4*>(&u[(size_t)s1 * 64 + c * 8]);
#pragma unroll
            for (int j = 0; j < 4; ++j)
                hacc[j] = __hadd2(hacc[j], __hadd2(a0.h[j], a1.h[j]));
            e += 16;
        }
        if (e < end) {
            int s = col[e];
            Pk a0;
            a0.f = *reinterpret_cast<const float4*>(&u[(size_t)s * 64 + c * 8]);
#pragma unroll
            for (int j = 0; j < 4; ++j)
                hacc[j] = __hadd2(hacc[j], a0.h[j]);
        }
#pragma unroll
        for (int m = 8; m <= 32; m <<= 1) {
#pragma unroll
            for (int j = 0; j < 4; ++j) {
                int t = __shfl_xor(*reinterpret_cast<int*>(&hacc[j]), m);
                hacc[j] = __hadd2(hacc[j], *reinterpret_cast<__half2*>(&t));
            }
        }
        if (r == 0) {
            union Pk2 { float4 f; __half2 h[4]; } sf;
            sf.f = *reinterpret_cast<const float4*>(&u[(size_t)node * 64 + c * 8]);
            float di = dinv[node];
            float4 b0 = *reinterpret_cast<const float4*>(&bias[c * 8]);
            float4 b1 = *reinterpret_cast<const float4*>(&bias[c * 8 + 4]);
#pragma unroll
            for (int j = 0; j < 4; ++j) {
                float2 a = __half22float2(hacc[j]);
                float2 t = __half22float2(sf.h[j]);
                o[2 * j]     = di * (a.x + t.x);
                o[2 * j + 1] = di * (a.y + t.y);
            }
            o[0] += b0.x; o[1] += b0.y; o[2] += b0.z; o[3] += b0.w;
            o[4] += b1.x; o[5] += b1.y; o[6] += b1.z; o[7] += b1.w;
            if (RELU) {
#pragma unroll
                for (int j = 0; j < 8; ++j) o[j] = fmaxf(o[j], 0.f);
            }
        }
    }

    if (!POOL) {
        if (r == 0) {
            float4 w0 = make_float4(o[0], o[1], o[2], o[3]);
            float4 w1 = make_float4(o[4], o[5], o[6], o[7]);
            *reinterpret_cast<float4*>(&H[(size_t)node * 64 + c * 8])     = w0;
            *reinterpret_cast<float4*>(&H[(size_t)node * 64 + c * 8 + 4]) = w1;
        }
    } else {
        if (r == 0) {
#pragma unroll
            for (int j = 0; j < 8; ++j) sh[wid][c * 8 + j] = o[j];   // zeros if invalid
        }
        if (lane == 0) sg[wid] = valid ? batch[node] : -1;
        __syncthreads();
        if (threadIdx.x < 64) {
            float s = 0.f;
            int gp = -1;
            for (int w = 0; w < 4; ++w) {
                int g = sg[w];
                if (g < 0) continue;
                if (g != gp) {
                    if (gp >= 0) atomicAdd(&pooled[gp * 64 + threadIdx.x], s);
                    s = 0.f;
                    gp = g;
                }
                s += sh[w][threadIdx.x];
            }
            if (gp >= 0) atomicAdd(&pooled[gp * 64 + threadIdx.x], s);
        }
    }
}

// ---------- head: counts via binary search, mean, folded MLP, softmax over graphs ----------
__global__ __launch_bounds__(512) void head_kernel(const float* __restrict__ pooled,
                                                   const int* __restrict__ batch,
                                                   const float* __restrict__ Wl1,
                                                   const float* __restrict__ bl1,
                                                   const float* __restrict__ Wl2,
                                                   const float* __restrict__ bl2,
                                                   float* __restrict__ out, int N) {
    __shared__ float Weff[64 * 2];
    __shared__ float beff[2];
    __shared__ float red[512];
    int tid = threadIdx.x;
    if (tid < 128) {
        int c = tid >> 1, j = tid & 1;
        float s = 0.f;
        for (int k = 0; k < 32; ++k) s += Wl1[c * 32 + k] * Wl2[k * 2 + j];
        Weff[c * 2 + j] = s;
    }
    if (tid < 2) {
        float s = bl2[tid];
        for (int k = 0; k < 32; ++k) s += bl1[k] * Wl2[k * 2 + tid];
        beff[tid] = s;
    }
    __syncthreads();

    int g = tid;
    auto lb = [&](int key) {
        int l = 0, r = N;
        while (l < r) { int m = (l + r) >> 1; if (batch[m] < key) l = m + 1; else r = m; }
        return l;
    };
    int cnt = lb(g + 1) - lb(g);
    float cn = fmaxf((float)cnt, 1.f);
    float z0 = beff[0], z1 = beff[1];
    for (int c = 0; c < 64; ++c) {
        float p = pooled[g * 64 + c] / cn;
        z0 += p * Weff[c * 2 + 0];
        z1 += p * Weff[c * 2 + 1];
    }

    red[tid] = z0; __syncthreads();
    for (int s = 256; s > 0; s >>= 1) { if (tid < s) red[tid] = fmaxf(red[tid], red[tid + s]); __syncthreads(); }
    float m0 = red[0]; __syncthreads();
    float e0 = expf(z0 - m0);
    red[tid] = e0; __syncthreads();
    for (int s = 256; s > 0; s >>= 1) { if (tid < s) red[tid] += red[tid + s]; __syncthreads(); }
    float s0 = red[0]; __syncthreads();
    out[g * 2 + 0] = e0 / s0;

    red[tid] = z1; __syncthreads();
    for (int s = 256; s > 0; s >>= 1) { if (tid < s) red[tid] = fmaxf(red[tid], red[tid + s]); __syncthreads(); }
    float m1 = red[0]; __syncthreads();
    float e1 = expf(z1 - m1);
    red[tid] = e1; __syncthreads();
    for (int s = 256; s > 0; s >>= 1) { if (tid < s) red[tid] += red[tid + s]; __syncthreads(); }
    float s1 = red[0]; __syncthreads();
    out[g * 2 + 1] = e1 / s1;
}

// ---------- launch ----------
extern "C" void kernel_launch(void* const* d_in, const int* in_sizes, int n_in,
                              void* d_out, int out_size, void* d_ws, size_t ws_size,
                              hipStream_t stream) {
    const float* x   = (const float*)d_in[0];
    const int*   ei  = (const int*)d_in[1];
    const int*   bat = (const int*)d_in[2];
    const float* W1  = (const float*)d_in[3];
    const float* b1  = (const float*)d_in[4];
    const float* W2  = (const float*)d_in[5];
    const float* b2  = (const float*)d_in[6];
    const float* Wl1 = (const float*)d_in[7];
    const float* bl1 = (const float*)d_in[8];
    const float* Wl2 = (const float*)d_in[9];
    const float* bl2 = (const float*)d_in[10];
    float* out = (float*)d_out;

    const int N = N_NODES, E = N_EDGES;
    const int* src = ei;
    const int* dst = ei + E;

    size_t o = 0;
    auto alloc = [&](size_t bytes) {
        void* p = (char*)d_ws + o;
        o += (bytes + 255) / 256 * 256;
        return p;
    };
    int*          pcnt   = (int*)alloc((size_t)SBLOCKS * NB * 4);
    int*          btot   = (int*)alloc((size_t)NB * 4);
    int*          bbase  = (int*)alloc((size_t)(NB + 1) * 4);
    int*          off    = (int*)alloc((size_t)(N + 1) * 4);
    float*        dinv   = (float*)alloc((size_t)N * 4);
    unsigned int* pairs  = (unsigned int*)alloc((size_t)E * 4);
    int*          col    = (int*)alloc((size_t)E * 4);
    __half*       T      = (__half*)alloc((size_t)N * 64 * 2);
    float*        H      = (float*)alloc((size_t)N * 64 * 4);
    float*        pooled = (float*)alloc((size_t)N_GRAPHS * 64 * 4);

    // per-call zeroing of atomic targets (ws is not re-poisoned between replays)
    hipMemsetAsync(pooled, 0, (size_t)N_GRAPHS * 64 * 4, stream);

    // CSR build: per-block histogram -> 2-level scan -> scatter -> per-bucket phase sort
    phist_kernel<<<SBLOCKS, 256, 0, stream>>>(dst, pcnt, E);
    pscanA_kernel<<<NB, 256, 0, stream>>>(pcnt, btot);
    pscanB_kernel<<<1, 512, 0, stream>>>(btot, bbase, off + N, E);
    scatter2_kernel<<<SBLOCKS, 256, 0, stream>>>(src, dst, pcnt, bbase, pairs, E);
    bucket_kernel<<<NB, 256, 0, stream>>>(pairs, bbase, col, off, dinv, N);

    // layer 1: U = half(dinv * (x @ W1)) ; H = relu(dinv * (sum + self) + b1)
    lin_kernel<128><<<N / 32, 256, 0, stream>>>(x, W1, dinv, T);
    agg_kernel<true, false><<<(N + 3) / 4, 256, 0, stream>>>(T, off, col, dinv, b1, H, nullptr, nullptr, N);

    // layer 2 (pooling fused into aggregation)
    lin_kernel<64><<<N / 32, 256, 0, stream>>>(H, W2, dinv, T);
    agg_kernel<false, true><<<(N + 3) / 4, 256, 0, stream>>>(T, off, col, dinv, b2, nullptr, pooled, bat, N);

    // head: counts + mean + folded MLP + softmax over graphs
    head_kernel<<<1, 512, 0, stream>>>(pooled, bat, Wl1, bl1, Wl2, bl2, out, N);
}

// Round 6
// 302.987 us; speedup vs baseline: 3.6521x; 1.0303x over previous
//
#include <hip/hip_runtime.h>
#include <hip/hip_fp16.h>
#include <math.h>

#define N_NODES 100000
#define N_EDGES 3200000
#define N_GRAPHS 512

#define BSHIFT 8
#define BSPAN 256                      // nodes per bucket
#define NB 391                         // ceil(N_NODES / BSPAN)
#define SBLK 16384                     // edges per scatter block
#define SBLOCKS ((N_EDGES + SBLK - 1) / SBLK)   // 196

typedef float floatx2 __attribute__((ext_vector_type(2)));

// ---------- pass 1: per-block bucket histogram -> pcnt[block][bucket] ----------
__global__ __launch_bounds__(256) void phist_kernel(const int* __restrict__ dst,
                                                    int* __restrict__ pcnt, int E) {
    __shared__ int h[NB];
    int tid = threadIdx.x;
    for (int b = tid; b < NB; b += 256) h[b] = 0;
    __syncthreads();
    int base = blockIdx.x * SBLK;
    int end = min(E, base + SBLK);
    for (int e = base + tid; e < end; e += 256)
        atomicAdd(&h[dst[e] >> BSHIFT], 1);
    __syncthreads();
    int* row = pcnt + (size_t)blockIdx.x * NB;
    for (int b = tid; b < NB; b += 256) row[b] = h[b];
}

// ---------- pass 2a: per-bucket scan over blocks (block b handles bucket b) ----------
__global__ __launch_bounds__(256) void pscanA_kernel(int* __restrict__ pcnt,
                                                     int* __restrict__ btot) {
    __shared__ int s[256];
    int b = blockIdx.x, tid = threadIdx.x;
    int v = (tid < SBLOCKS) ? pcnt[(size_t)tid * NB + b] : 0;
    s[tid] = v;
    __syncthreads();
    for (int st = 1; st < 256; st <<= 1) {
        int t = (tid >= st) ? s[tid - st] : 0;
        __syncthreads();
        s[tid] += t;
        __syncthreads();
    }
    int excl = s[tid] - v;
    if (tid < SBLOCKS) pcnt[(size_t)tid * NB + b] = excl;
    if (tid == SBLOCKS - 1) btot[b] = excl + v;
}

// ---------- pass 2b: scan bucket totals -> bbase ----------
__global__ __launch_bounds__(512) void pscanB_kernel(const int* __restrict__ btot,
                                                     int* __restrict__ bbase,
                                                     int* __restrict__ offN, int E) {
    __shared__ int s[512];
    int tid = threadIdx.x;
    int v = (tid < NB) ? btot[tid] : 0;
    s[tid] = v;
    __syncthreads();
    for (int st = 1; st < 512; st <<= 1) {
        int t = (tid >= st) ? s[tid - st] : 0;
        __syncthreads();
        s[tid] += t;
        __syncthreads();
    }
    int excl = s[tid] - v;
    if (tid < NB) bbase[tid] = excl;
    if (tid == NB - 1) bbase[NB] = excl + v;
    if (tid == 0) *offN = E;
}

// ---------- pass 3: scatter edges into bucket segments (packed 32-bit) ----------
__global__ __launch_bounds__(256) void scatter2_kernel(const int* __restrict__ src,
                                                       const int* __restrict__ dst,
                                                       const int* __restrict__ pbase,
                                                       const int* __restrict__ bbase,
                                                       unsigned int* __restrict__ pairs, int E) {
    __shared__ int hrank[NB];
    __shared__ int hb[NB];
    int tid = threadIdx.x;
    const int* row = pbase + (size_t)blockIdx.x * NB;
    for (int b = tid; b < NB; b += 256) { hrank[b] = 0; hb[b] = row[b] + bbase[b]; }
    __syncthreads();
    int base = blockIdx.x * SBLK;
    int end = min(E, base + SBLK);
    for (int e = base + tid; e < end; e += 256) {
        int d = dst[e];
        int b = d >> BSHIFT;
        int rk = atomicAdd(&hrank[b], 1);
        pairs[hb[b] + rk] = ((unsigned int)src[e] << BSHIFT) | (unsigned int)(d & (BSPAN - 1));
    }
}

// ---------- pass 4: per-bucket fine sort -> col, off, dinv ----------
__global__ __launch_bounds__(256) void bucket_kernel(const unsigned int* __restrict__ pairs,
                                                     const int* __restrict__ bbase,
                                                     int* __restrict__ col,
                                                     int* __restrict__ off,
                                                     float* __restrict__ dinv, int N) {
    __shared__ int ncnt[BSPAN];
    __shared__ int nbase[BSPAN];
    __shared__ int a[BSPAN];
    int b = blockIdx.x, tid = threadIdx.x;
    int base = bbase[b];
    int cntb = bbase[b + 1] - base;
    int n0 = b << BSHIFT;
    int nn = min(BSPAN, N - n0);
    ncnt[tid] = 0;
    __syncthreads();
    for (int i = tid; i < cntb; i += 256)
        atomicAdd(&ncnt[pairs[base + i] & (BSPAN - 1)], 1);
    __syncthreads();
    int v = ncnt[tid];
    a[tid] = v;
    __syncthreads();
    for (int st = 1; st < 256; st <<= 1) {
        int t = (tid >= st) ? a[tid - st] : 0;
        __syncthreads();
        a[tid] += t;
        __syncthreads();
    }
    nbase[tid] = a[tid] - v;
    if (tid < nn) {
        off[n0 + tid] = base + nbase[tid];
        dinv[n0 + tid] = rsqrtf((float)(v + 1));   // +1 self loop
    }
    ncnt[tid] = 0;   // reuse as cursor
    __syncthreads();
    for (int i = tid; i < cntb; i += 256) {
        unsigned int p = pairs[base + i];
        int dl = p & (BSPAN - 1);
        int pos = base + nbase[dl] + atomicAdd(&ncnt[dl], 1);
        col[pos] = (int)(p >> BSHIFT);
    }
}

// ---------- dense linear: U[n,64] = fp8(dinv[n] * (X[n,K] @ W[K,64])) ----------
template <int K, typename TX>
__global__ __launch_bounds__(256) void lin_kernel(const TX* __restrict__ X,
                                                  const float* __restrict__ W,
                                                  const float* __restrict__ rs,
                                                  unsigned char* __restrict__ U) {
    __shared__ float Ws[K * 64];
    __shared__ float Xs[32 * K];
    int tid = threadIdx.x;
    for (int i = tid * 4; i < K * 64; i += 256 * 4)
        *reinterpret_cast<float4*>(&Ws[i]) = *reinterpret_cast<const float4*>(&W[i]);
    int row0 = blockIdx.x * 32;
    const TX* Xbase = X + (size_t)row0 * K;
    if constexpr (sizeof(TX) == 4) {
        for (int i = tid * 4; i < 32 * K; i += 256 * 4)
            *reinterpret_cast<float4*>(&Xs[i]) =
                *reinterpret_cast<const float4*>(&Xbase[i]);
    } else {
        for (int i = tid * 8; i < 32 * K; i += 256 * 8) {
            int4 v = *reinterpret_cast<const int4*>(&Xbase[i]);
            const __half2* hp = reinterpret_cast<const __half2*>(&v);
#pragma unroll
            for (int j = 0; j < 4; ++j) {
                float2 f = __half22float2(hp[j]);
                Xs[i + 2 * j]     = f.x;
                Xs[i + 2 * j + 1] = f.y;
            }
        }
    }
    __syncthreads();

    int wid = tid >> 6, lane = tid & 63;
    int rbase = wid * 8;
    float acc[8];
#pragma unroll
    for (int r = 0; r < 8; ++r) acc[r] = 0.f;

    for (int k4 = 0; k4 < K / 4; ++k4) {
        float w0 = Ws[(k4 * 4 + 0) * 64 + lane];
        float w1 = Ws[(k4 * 4 + 1) * 64 + lane];
        float w2 = Ws[(k4 * 4 + 2) * 64 + lane];
        float w3 = Ws[(k4 * 4 + 3) * 64 + lane];
#pragma unroll
        for (int r = 0; r < 8; ++r) {
            float4 xv = *reinterpret_cast<const float4*>(&Xs[(rbase + r) * K + k4 * 4]);
            acc[r] += xv.x * w0 + xv.y * w1 + xv.z * w2 + xv.w * w3;
        }
    }
#pragma unroll
    for (int r = 0; r < 8; ++r) {
        int row = row0 + rbase + r;
        float v = acc[r] * rs[row];
        int pk = __builtin_amdgcn_cvt_pk_fp8_f32(v, v, 0, false);
        U[(size_t)row * 64 + lane] = (unsigned char)(pk & 0xff);
    }
}

// ---------- aggregation: wave = node, 8 lanes/edge x 8 edge slots, fp8 rows (64B),
// f32 accumulate, 4-deep unroll. POOL=true: accumulate into pooled[] ----------
#define ACC8(a)                                                                  \
    {                                                                            \
        floatx2 f_;                                                              \
        f_ = __builtin_amdgcn_cvt_pk_f32_fp8((int)(a).x, false);                 \
        acc[0] += f_.x; acc[1] += f_.y;                                          \
        f_ = __builtin_amdgcn_cvt_pk_f32_fp8((int)(a).x, true);                  \
        acc[2] += f_.x; acc[3] += f_.y;                                          \
        f_ = __builtin_amdgcn_cvt_pk_f32_fp8((int)(a).y, false);                 \
        acc[4] += f_.x; acc[5] += f_.y;                                          \
        f_ = __builtin_amdgcn_cvt_pk_f32_fp8((int)(a).y, true);                  \
        acc[6] += f_.x; acc[7] += f_.y;                                          \
    }

template <bool RELU, bool POOL>
__global__ __launch_bounds__(256) void agg_kernel(const unsigned char* __restrict__ u,
                                                  const int* __restrict__ off,
                                                  const int* __restrict__ col,
                                                  const float* __restrict__ dinv,
                                                  const float* __restrict__ bias,
                                                  __half* __restrict__ H,
                                                  float* __restrict__ pooled,
                                                  const int* __restrict__ batch, int n) {
    __shared__ float sh[4][64];
    __shared__ int sg[4];
    int wid = threadIdx.x >> 6, lane = threadIdx.x & 63;
    int node = blockIdx.x * 4 + wid;
    bool valid = node < n;
    if (!POOL && !valid) return;
    int r = lane >> 3, c = lane & 7;   // edge slot, feat group (8 feats of 64)
    float o[8];
#pragma unroll
    for (int j = 0; j < 8; ++j) o[j] = 0.f;

    if (valid) {
        int beg = off[node], end = off[node + 1];
        float acc[8];
#pragma unroll
        for (int j = 0; j < 8; ++j) acc[j] = 0.f;
        int e = beg + r;
        while (e + 24 < end) {
            int s0 = col[e], s1 = col[e + 8], s2 = col[e + 16], s3 = col[e + 24];
            uint2 a0 = *reinterpret_cast<const uint2*>(u + (size_t)s0 * 64 + c * 8);
            uint2 a1 = *reinterpret_cast<const uint2*>(u + (size_t)s1 * 64 + c * 8);
            uint2 a2 = *reinterpret_cast<const uint2*>(u + (size_t)s2 * 64 + c * 8);
            uint2 a3 = *reinterpret_cast<const uint2*>(u + (size_t)s3 * 64 + c * 8);
            ACC8(a0); ACC8(a1); ACC8(a2); ACC8(a3);
            e += 32;
        }
        while (e + 8 < end) {
            int s0 = col[e], s1 = col[e + 8];
            uint2 a0 = *reinterpret_cast<const uint2*>(u + (size_t)s0 * 64 + c * 8);
            uint2 a1 = *reinterpret_cast<const uint2*>(u + (size_t)s1 * 64 + c * 8);
            ACC8(a0); ACC8(a1);
            e += 16;
        }
        if (e < end) {
            int s0 = col[e];
            uint2 a0 = *reinterpret_cast<const uint2*>(u + (size_t)s0 * 64 + c * 8);
            ACC8(a0);
        }
#pragma unroll
        for (int m = 8; m <= 32; m <<= 1) {
#pragma unroll
            for (int j = 0; j < 8; ++j) acc[j] += __shfl_xor(acc[j], m);
        }
        if (r == 0) {
            uint2 sfr = *reinterpret_cast<const uint2*>(u + (size_t)node * 64 + c * 8);
            ACC8(sfr);   // add self row into acc
            float di = dinv[node];
            float4 b0 = *reinterpret_cast<const float4*>(&bias[c * 8]);
            float4 b1 = *reinterpret_cast<const float4*>(&bias[c * 8 + 4]);
#pragma unroll
            for (int j = 0; j < 8; ++j) o[j] = di * acc[j];
            o[0] += b0.x; o[1] += b0.y; o[2] += b0.z; o[3] += b0.w;
            o[4] += b1.x; o[5] += b1.y; o[6] += b1.z; o[7] += b1.w;
            if (RELU) {
#pragma unroll
                for (int j = 0; j < 8; ++j) o[j] = fmaxf(o[j], 0.f);
            }
        }
    }

    if (!POOL) {
        if (r == 0) {
            __half2 hw[4];
#pragma unroll
            for (int j = 0; j < 4; ++j)
                hw[j] = __floats2half2_rn(o[2 * j], o[2 * j + 1]);
            *reinterpret_cast<int4*>(&H[(size_t)node * 64 + c * 8]) =
                *reinterpret_cast<const int4*>(hw);
        }
    } else {
        if (r == 0) {
#pragma unroll
            for (int j = 0; j < 8; ++j) sh[wid][c * 8 + j] = o[j];   // zeros if invalid
        }
        if (lane == 0) sg[wid] = valid ? batch[node] : -1;
        __syncthreads();
        if (threadIdx.x < 64) {
            float s = 0.f;
            int gp = -1;
            for (int w = 0; w < 4; ++w) {
                int g = sg[w];
                if (g < 0) continue;
                if (g != gp) {
                    if (gp >= 0) atomicAdd(&pooled[gp * 64 + threadIdx.x], s);
                    s = 0.f;
                    gp = g;
                }
                s += sh[w][threadIdx.x];
            }
            if (gp >= 0) atomicAdd(&pooled[gp * 64 + threadIdx.x], s);
        }
    }
}

// ---------- head: counts via binary search, mean, folded MLP, softmax over graphs ----------
__global__ __launch_bounds__(512) void head_kernel(const float* __restrict__ pooled,
                                                   const int* __restrict__ batch,
                                                   const float* __restrict__ Wl1,
                                                   const float* __restrict__ bl1,
                                                   const float* __restrict__ Wl2,
                                                   const float* __restrict__ bl2,
                                                   float* __restrict__ out, int N) {
    __shared__ float Weff[64 * 2];
    __shared__ float beff[2];
    __shared__ float red[512];
    int tid = threadIdx.x;
    if (tid < 128) {
        int c = tid >> 1, j = tid & 1;
        float s = 0.f;
        for (int k = 0; k < 32; ++k) s += Wl1[c * 32 + k] * Wl2[k * 2 + j];
        Weff[c * 2 + j] = s;
    }
    if (tid < 2) {
        float s = bl2[tid];
        for (int k = 0; k < 32; ++k) s += bl1[k] * Wl2[k * 2 + tid];
        beff[tid] = s;
    }
    __syncthreads();

    int g = tid;
    auto lb = [&](int key) {
        int l = 0, r = N;
        while (l < r) { int m = (l + r) >> 1; if (batch[m] < key) l = m + 1; else r = m; }
        return l;
    };
    int cnt = lb(g + 1) - lb(g);
    float cn = fmaxf((float)cnt, 1.f);
    float z0 = beff[0], z1 = beff[1];
    for (int c = 0; c < 64; ++c) {
        float p = pooled[g * 64 + c] / cn;
        z0 += p * Weff[c * 2 + 0];
        z1 += p * Weff[c * 2 + 1];
    }

    red[tid] = z0; __syncthreads();
    for (int s = 256; s > 0; s >>= 1) { if (tid < s) red[tid] = fmaxf(red[tid], red[tid + s]); __syncthreads(); }
    float m0 = red[0]; __syncthreads();
    float e0 = expf(z0 - m0);
    red[tid] = e0; __syncthreads();
    for (int s = 256; s > 0; s >>= 1) { if (tid < s) red[tid] += red[tid + s]; __syncthreads(); }
    float s0 = red[0]; __syncthreads();
    out[g * 2 + 0] = e0 / s0;

    red[tid] = z1; __syncthreads();
    for (int s = 256; s > 0; s >>= 1) { if (tid < s) red[tid] = fmaxf(red[tid], red[tid + s]); __syncthreads(); }
    float m1 = red[0]; __syncthreads();
    float e1 = expf(z1 - m1);
    red[tid] = e1; __syncthreads();
    for (int s = 256; s > 0; s >>= 1) { if (tid < s) red[tid] += red[tid + s]; __syncthreads(); }
    float s1 = red[0]; __syncthreads();
    out[g * 2 + 1] = e1 / s1;
}

// ---------- launch ----------
extern "C" void kernel_launch(void* const* d_in, const int* in_sizes, int n_in,
                              void* d_out, int out_size, void* d_ws, size_t ws_size,
                              hipStream_t stream) {
    const float* x   = (const float*)d_in[0];
    const int*   ei  = (const int*)d_in[1];
    const int*   bat = (const int*)d_in[2];
    const float* W1  = (const float*)d_in[3];
    const float* b1  = (const float*)d_in[4];
    const float* W2  = (const float*)d_in[5];
    const float* b2  = (const float*)d_in[6];
    const float* Wl1 = (const float*)d_in[7];
    const float* bl1 = (const float*)d_in[8];
    const float* Wl2 = (const float*)d_in[9];
    const float* bl2 = (const float*)d_in[10];
    float* out = (float*)d_out;

    const int N = N_NODES, E = N_EDGES;
    const int* src = ei;
    const int* dst = ei + E;

    size_t o = 0;
    auto alloc = [&](size_t bytes) {
        void* p = (char*)d_ws + o;
        o += (bytes + 255) / 256 * 256;
        return p;
    };
    int*           pcnt   = (int*)alloc((size_t)SBLOCKS * NB * 4);
    int*           btot   = (int*)alloc((size_t)NB * 4);
    int*           bbase  = (int*)alloc((size_t)(NB + 1) * 4);
    int*           off    = (int*)alloc((size_t)(N + 1) * 4);
    float*         dinv   = (float*)alloc((size_t)N * 4);
    unsigned int*  pairs  = (unsigned int*)alloc((size_t)E * 4);
    int*           col    = (int*)alloc((size_t)E * 4);
    unsigned char* T      = (unsigned char*)alloc((size_t)N * 64);
    __half*        H      = (__half*)alloc((size_t)N * 64 * 2);
    float*         pooled = (float*)alloc((size_t)N_GRAPHS * 64 * 4);

    // per-call zeroing of atomic targets (ws is not re-poisoned between replays)
    hipMemsetAsync(pooled, 0, (size_t)N_GRAPHS * 64 * 4, stream);

    // CSR build: per-block histogram -> 2-level scan -> scatter -> per-bucket sort
    phist_kernel<<<SBLOCKS, 256, 0, stream>>>(dst, pcnt, E);
    pscanA_kernel<<<NB, 256, 0, stream>>>(pcnt, btot);
    pscanB_kernel<<<1, 512, 0, stream>>>(btot, bbase, off + N, E);
    scatter2_kernel<<<SBLOCKS, 256, 0, stream>>>(src, dst, pcnt, bbase, pairs, E);
    bucket_kernel<<<NB, 256, 0, stream>>>(pairs, bbase, col, off, dinv, N);

    // layer 1: U = fp8(dinv * (x @ W1)) ; H = fp16(relu(dinv * (sum + self) + b1))
    lin_kernel<128, float><<<N / 32, 256, 0, stream>>>(x, W1, dinv, T);
    agg_kernel<true, false><<<(N + 3) / 4, 256, 0, stream>>>(T, off, col, dinv, b1, H, nullptr, nullptr, N);

    // layer 2 (pooling fused into aggregation)
    lin_kernel<64, __half><<<N / 32, 256, 0, stream>>>(H, W2, dinv, T);
    agg_kernel<false, true><<<(N + 3) / 4, 256, 0, stream>>>(T, off, col, dinv, b2, nullptr, pooled, bat, N);

    // head: counts + mean + folded MLP + softmax over graphs
    head_kernel<<<1, 512, 0, stream>>>(pooled, bat, Wl1, bl1, Wl2, bl2, out, N);
}

// Round 7
// 286.523 us; speedup vs baseline: 3.8620x; 1.0575x over previous
//
#include <hip/hip_runtime.h>
#include <hip/hip_fp16.h>
#include <math.h>

#define N_NODES 100000
#define N_EDGES 3200000
#define N_GRAPHS 512

#define BSHIFT 8
#define BSPAN 256                      // nodes per bucket
#define NB 391                         // ceil(N_NODES / BSPAN)
#define SBLK 4096                      // edges per scatter block
#define SBLOCKS ((N_EDGES + SBLK - 1) / SBLK)   // 782
#define SCAN_IT ((SBLOCKS + 255) / 256)         // 4

typedef float floatx2 __attribute__((ext_vector_type(2)));

// ---------- pass 1: per-block bucket histogram -> pcnt[block][bucket] ----------
__global__ __launch_bounds__(256) void phist_kernel(const int* __restrict__ dst,
                                                    int* __restrict__ pcnt, int E) {
    __shared__ int h[NB];
    int tid = threadIdx.x;
    for (int b = tid; b < NB; b += 256) h[b] = 0;
    __syncthreads();
    int base = blockIdx.x * SBLK;
    int end = min(E, base + SBLK);
    for (int e = base + tid; e < end; e += 256)
        atomicAdd(&h[dst[e] >> BSHIFT], 1);
    __syncthreads();
    int* row = pcnt + (size_t)blockIdx.x * NB;
    for (int b = tid; b < NB; b += 256) row[b] = h[b];
}

// ---------- pass 2a: per-bucket scan over blocks (block b handles bucket b) ----------
__global__ __launch_bounds__(256) void pscanA_kernel(int* __restrict__ pcnt,
                                                     int* __restrict__ btot) {
    __shared__ int s[256];
    int b = blockIdx.x, tid = threadIdx.x;
    int v[SCAN_IT];
    int sum = 0;
#pragma unroll
    for (int j = 0; j < SCAN_IT; ++j) {
        int idx = tid * SCAN_IT + j;
        v[j] = (idx < SBLOCKS) ? pcnt[(size_t)idx * NB + b] : 0;
        sum += v[j];
    }
    s[tid] = sum;
    __syncthreads();
    for (int st = 1; st < 256; st <<= 1) {
        int t = (tid >= st) ? s[tid - st] : 0;
        __syncthreads();
        s[tid] += t;
        __syncthreads();
    }
    int run = s[tid] - sum;
#pragma unroll
    for (int j = 0; j < SCAN_IT; ++j) {
        int idx = tid * SCAN_IT + j;
        if (idx < SBLOCKS) pcnt[(size_t)idx * NB + b] = run;
        run += v[j];
    }
    if (tid == 255) btot[b] = run;
}

// ---------- pass 2b: scan bucket totals -> bbase ----------
__global__ __launch_bounds__(512) void pscanB_kernel(const int* __restrict__ btot,
                                                     int* __restrict__ bbase,
                                                     int* __restrict__ offN, int E) {
    __shared__ int s[512];
    int tid = threadIdx.x;
    int v = (tid < NB) ? btot[tid] : 0;
    s[tid] = v;
    __syncthreads();
    for (int st = 1; st < 512; st <<= 1) {
        int t = (tid >= st) ? s[tid - st] : 0;
        __syncthreads();
        s[tid] += t;
        __syncthreads();
    }
    int excl = s[tid] - v;
    if (tid < NB) bbase[tid] = excl;
    if (tid == NB - 1) bbase[NB] = excl + v;
    if (tid == 0) *offN = E;
}

// ---------- pass 3: scatter edges into bucket segments (packed 32-bit) ----------
__global__ __launch_bounds__(256) void scatter2_kernel(const int* __restrict__ src,
                                                       const int* __restrict__ dst,
                                                       const int* __restrict__ pbase,
                                                       const int* __restrict__ bbase,
                                                       unsigned int* __restrict__ pairs, int E) {
    __shared__ int hrank[NB];
    __shared__ int hb[NB];
    int tid = threadIdx.x;
    const int* row = pbase + (size_t)blockIdx.x * NB;
    for (int b = tid; b < NB; b += 256) { hrank[b] = 0; hb[b] = row[b] + bbase[b]; }
    __syncthreads();
    int base = blockIdx.x * SBLK;
    int end = min(E, base + SBLK);
    for (int e = base + tid; e < end; e += 256) {
        int d = dst[e];
        int b = d >> BSHIFT;
        int rk = atomicAdd(&hrank[b], 1);
        pairs[hb[b] + rk] = ((unsigned int)src[e] << BSHIFT) | (unsigned int)(d & (BSPAN - 1));
    }
}

// ---------- pass 4: per-bucket fine sort -> col (byte offsets), off, dinv ----------
__global__ __launch_bounds__(256) void bucket_kernel(const unsigned int* __restrict__ pairs,
                                                     const int* __restrict__ bbase,
                                                     int* __restrict__ col,
                                                     int* __restrict__ off,
                                                     float* __restrict__ dinv, int N) {
    __shared__ int ncnt[BSPAN];
    __shared__ int nbase[BSPAN];
    __shared__ int a[BSPAN];
    int b = blockIdx.x, tid = threadIdx.x;
    int base = bbase[b];
    int cntb = bbase[b + 1] - base;
    int n0 = b << BSHIFT;
    int nn = min(BSPAN, N - n0);
    ncnt[tid] = 0;
    __syncthreads();
    for (int i = tid; i < cntb; i += 256)
        atomicAdd(&ncnt[pairs[base + i] & (BSPAN - 1)], 1);
    __syncthreads();
    int v = ncnt[tid];
    a[tid] = v;
    __syncthreads();
    for (int st = 1; st < 256; st <<= 1) {
        int t = (tid >= st) ? a[tid - st] : 0;
        __syncthreads();
        a[tid] += t;
        __syncthreads();
    }
    nbase[tid] = a[tid] - v;
    if (tid < nn) {
        off[n0 + tid] = base + nbase[tid];
        dinv[n0 + tid] = rsqrtf((float)(v + 1));   // +1 self loop
    }
    ncnt[tid] = 0;   // reuse as cursor
    __syncthreads();
    for (int i = tid; i < cntb; i += 256) {
        unsigned int p = pairs[base + i];
        int dl = p & (BSPAN - 1);
        int pos = base + nbase[dl] + atomicAdd(&ncnt[dl], 1);
        col[pos] = (int)(p >> BSHIFT) << 6;   // pre-shifted byte offset into u
    }
}

// ---------- dense linear: U[n,64] = fp8(dinv[n] * (X[n,K] @ W[K,64])) ----------
template <int K, typename TX>
__global__ __launch_bounds__(256) void lin_kernel(const TX* __restrict__ X,
                                                  const float* __restrict__ W,
                                                  const float* __restrict__ rs,
                                                  unsigned char* __restrict__ U) {
    __shared__ float Ws[K * 64];
    __shared__ float Xs[32 * K];
    int tid = threadIdx.x;
    for (int i = tid * 4; i < K * 64; i += 256 * 4)
        *reinterpret_cast<float4*>(&Ws[i]) = *reinterpret_cast<const float4*>(&W[i]);
    int row0 = blockIdx.x * 32;
    const TX* Xbase = X + (size_t)row0 * K;
    if constexpr (sizeof(TX) == 4) {
        for (int i = tid * 4; i < 32 * K; i += 256 * 4)
            *reinterpret_cast<float4*>(&Xs[i]) =
                *reinterpret_cast<const float4*>(&Xbase[i]);
    } else {
        for (int i = tid * 8; i < 32 * K; i += 256 * 8) {
            int4 v = *reinterpret_cast<const int4*>(&Xbase[i]);
            const __half2* hp = reinterpret_cast<const __half2*>(&v);
#pragma unroll
            for (int j = 0; j < 4; ++j) {
                float2 f = __half22float2(hp[j]);
                Xs[i + 2 * j]     = f.x;
                Xs[i + 2 * j + 1] = f.y;
            }
        }
    }
    __syncthreads();

    int wid = tid >> 6, lane = tid & 63;
    int rbase = wid * 8;
    float acc[8];
#pragma unroll
    for (int r = 0; r < 8; ++r) acc[r] = 0.f;

    for (int k4 = 0; k4 < K / 4; ++k4) {
        float w0 = Ws[(k4 * 4 + 0) * 64 + lane];
        float w1 = Ws[(k4 * 4 + 1) * 64 + lane];
        float w2 = Ws[(k4 * 4 + 2) * 64 + lane];
        float w3 = Ws[(k4 * 4 + 3) * 64 + lane];
#pragma unroll
        for (int r = 0; r < 8; ++r) {
            float4 xv = *reinterpret_cast<const float4*>(&Xs[(rbase + r) * K + k4 * 4]);
            acc[r] += xv.x * w0 + xv.y * w1 + xv.z * w2 + xv.w * w3;
        }
    }
#pragma unroll
    for (int r = 0; r < 8; ++r) {
        int row = row0 + rbase + r;
        float v = acc[r] * rs[row];
        int pk = __builtin_amdgcn_cvt_pk_fp8_f32(v, v, 0, false);
        U[(size_t)row * 64 + lane] = (unsigned char)(pk & 0xff);
    }
}

// ---------- aggregation: wave = node, 8 lanes/edge x 8 edge slots, fp8 rows (64B),
// f32 accumulate, 32-bit voffset addressing. POOL=true: accumulate into pooled[] ----------
#define ACC8(a)                                                                  \
    {                                                                            \
        floatx2 f_;                                                              \
        f_ = __builtin_amdgcn_cvt_pk_f32_fp8((int)(a).x, false);                 \
        acc[0] += f_.x; acc[1] += f_.y;                                          \
        f_ = __builtin_amdgcn_cvt_pk_f32_fp8((int)(a).x, true);                  \
        acc[2] += f_.x; acc[3] += f_.y;                                          \
        f_ = __builtin_amdgcn_cvt_pk_f32_fp8((int)(a).y, false);                 \
        acc[4] += f_.x; acc[5] += f_.y;                                          \
        f_ = __builtin_amdgcn_cvt_pk_f32_fp8((int)(a).y, true);                  \
        acc[6] += f_.x; acc[7] += f_.y;                                          \
    }

template <bool RELU, bool POOL>
__global__ __launch_bounds__(256) void agg_kernel(const unsigned char* __restrict__ u,
                                                  const int* __restrict__ off,
                                                  const int* __restrict__ col,
                                                  const float* __restrict__ dinv,
                                                  const float* __restrict__ bias,
                                                  __half* __restrict__ H,
                                                  float* __restrict__ pooled,
                                                  const int* __restrict__ batch, int n) {
    __shared__ float sh[4][64];
    __shared__ int sg[4];
    int wid = threadIdx.x >> 6, lane = threadIdx.x & 63;
    int node = blockIdx.x * 4 + wid;
    bool valid = node < n;
    if (!POOL && !valid) return;
    int r = lane >> 3, c = lane & 7;   // edge slot, feat group (8 feats of 64)
    unsigned int c8 = (unsigned int)c * 8;
    float o[8];
#pragma unroll
    for (int j = 0; j < 8; ++j) o[j] = 0.f;

    if (valid) {
        int beg = off[node], end = off[node + 1];
        float acc[8];
#pragma unroll
        for (int j = 0; j < 8; ++j) acc[j] = 0.f;
        int e = beg + r;
        while (e + 24 < end) {
            unsigned int v0 = (unsigned int)col[e]      + c8;
            unsigned int v1 = (unsigned int)col[e + 8]  + c8;
            unsigned int v2 = (unsigned int)col[e + 16] + c8;
            unsigned int v3 = (unsigned int)col[e + 24] + c8;
            uint2 a0 = *reinterpret_cast<const uint2*>(u + v0);
            uint2 a1 = *reinterpret_cast<const uint2*>(u + v1);
            uint2 a2 = *reinterpret_cast<const uint2*>(u + v2);
            uint2 a3 = *reinterpret_cast<const uint2*>(u + v3);
            ACC8(a0); ACC8(a1); ACC8(a2); ACC8(a3);
            e += 32;
        }
        while (e + 8 < end) {
            unsigned int v0 = (unsigned int)col[e]     + c8;
            unsigned int v1 = (unsigned int)col[e + 8] + c8;
            uint2 a0 = *reinterpret_cast<const uint2*>(u + v0);
            uint2 a1 = *reinterpret_cast<const uint2*>(u + v1);
            ACC8(a0); ACC8(a1);
            e += 16;
        }
        if (e < end) {
            unsigned int v0 = (unsigned int)col[e] + c8;
            uint2 a0 = *reinterpret_cast<const uint2*>(u + v0);
            ACC8(a0);
        }
#pragma unroll
        for (int m = 8; m <= 32; m <<= 1) {
#pragma unroll
            for (int j = 0; j < 8; ++j) acc[j] += __shfl_xor(acc[j], m);
        }
        if (r == 0) {
            unsigned int vs = ((unsigned int)node << 6) + c8;
            uint2 sfr = *reinterpret_cast<const uint2*>(u + vs);
            ACC8(sfr);   // add self row into acc
            float di = dinv[node];
            float4 b0 = *reinterpret_cast<const float4*>(&bias[c * 8]);
            float4 b1 = *reinterpret_cast<const float4*>(&bias[c * 8 + 4]);
#pragma unroll
            for (int j = 0; j < 8; ++j) o[j] = di * acc[j];
            o[0] += b0.x; o[1] += b0.y; o[2] += b0.z; o[3] += b0.w;
            o[4] += b1.x; o[5] += b1.y; o[6] += b1.z; o[7] += b1.w;
            if (RELU) {
#pragma unroll
                for (int j = 0; j < 8; ++j) o[j] = fmaxf(o[j], 0.f);
            }
        }
    }

    if (!POOL) {
        if (r == 0) {
            __half2 hw[4];
#pragma unroll
            for (int j = 0; j < 4; ++j)
                hw[j] = __floats2half2_rn(o[2 * j], o[2 * j + 1]);
            *reinterpret_cast<int4*>(&H[(size_t)node * 64 + c * 8]) =
                *reinterpret_cast<const int4*>(hw);
        }
    } else {
        if (r == 0) {
#pragma unroll
            for (int j = 0; j < 8; ++j) sh[wid][c * 8 + j] = o[j];   // zeros if invalid
        }
        if (lane == 0) sg[wid] = valid ? batch[node] : -1;
        __syncthreads();
        if (threadIdx.x < 64) {
            float s = 0.f;
            int gp = -1;
            for (int w = 0; w < 4; ++w) {
                int g = sg[w];
                if (g < 0) continue;
                if (g != gp) {
                    if (gp >= 0) atomicAdd(&pooled[gp * 64 + threadIdx.x], s);
                    s = 0.f;
                    gp = g;
                }
                s += sh[w][threadIdx.x];
            }
            if (gp >= 0) atomicAdd(&pooled[gp * 64 + threadIdx.x], s);
        }
    }
}

// ---------- head: counts via binary search, mean, folded MLP, softmax over graphs ----------
__global__ __launch_bounds__(512) void head_kernel(const float* __restrict__ pooled,
                                                   const int* __restrict__ batch,
                                                   const float* __restrict__ Wl1,
                                                   const float* __restrict__ bl1,
                                                   const float* __restrict__ Wl2,
                                                   const float* __restrict__ bl2,
                                                   float* __restrict__ out, int N) {
    __shared__ float Weff[64 * 2];
    __shared__ float beff[2];
    __shared__ float red[512];
    int tid = threadIdx.x;
    if (tid < 128) {
        int c = tid >> 1, j = tid & 1;
        float s = 0.f;
        for (int k = 0; k < 32; ++k) s += Wl1[c * 32 + k] * Wl2[k * 2 + j];
        Weff[c * 2 + j] = s;
    }
    if (tid < 2) {
        float s = bl2[tid];
        for (int k = 0; k < 32; ++k) s += bl1[k] * Wl2[k * 2 + tid];
        beff[tid] = s;
    }
    __syncthreads();

    int g = tid;
    auto lb = [&](int key) {
        int l = 0, r = N;
        while (l < r) { int m = (l + r) >> 1; if (batch[m] < key) l = m + 1; else r = m; }
        return l;
    };
    int cnt = lb(g + 1) - lb(g);
    float cn = fmaxf((float)cnt, 1.f);
    float z0 = beff[0], z1 = beff[1];
    for (int c = 0; c < 64; ++c) {
        float p = pooled[g * 64 + c] / cn;
        z0 += p * Weff[c * 2 + 0];
        z1 += p * Weff[c * 2 + 1];
    }

    red[tid] = z0; __syncthreads();
    for (int s = 256; s > 0; s >>= 1) { if (tid < s) red[tid] = fmaxf(red[tid], red[tid + s]); __syncthreads(); }
    float m0 = red[0]; __syncthreads();
    float e0 = expf(z0 - m0);
    red[tid] = e0; __syncthreads();
    for (int s = 256; s > 0; s >>= 1) { if (tid < s) red[tid] += red[tid + s]; __syncthreads(); }
    float s0 = red[0]; __syncthreads();
    out[g * 2 + 0] = e0 / s0;

    red[tid] = z1; __syncthreads();
    for (int s = 256; s > 0; s >>= 1) { if (tid < s) red[tid] = fmaxf(red[tid], red[tid + s]); __syncthreads(); }
    float m1 = red[0]; __syncthreads();
    float e1 = expf(z1 - m1);
    red[tid] = e1; __syncthreads();
    for (int s = 256; s > 0; s >>= 1) { if (tid < s) red[tid] += red[tid + s]; __syncthreads(); }
    float s1 = red[0]; __syncthreads();
    out[g * 2 + 1] = e1 / s1;
}

// ---------- launch ----------
extern "C" void kernel_launch(void* const* d_in, const int* in_sizes, int n_in,
                              void* d_out, int out_size, void* d_ws, size_t ws_size,
                              hipStream_t stream) {
    const float* x   = (const float*)d_in[0];
    const int*   ei  = (const int*)d_in[1];
    const int*   bat = (const int*)d_in[2];
    const float* W1  = (const float*)d_in[3];
    const float* b1  = (const float*)d_in[4];
    const float* W2  = (const float*)d_in[5];
    const float* b2  = (const float*)d_in[6];
    const float* Wl1 = (const float*)d_in[7];
    const float* bl1 = (const float*)d_in[8];
    const float* Wl2 = (const float*)d_in[9];
    const float* bl2 = (const float*)d_in[10];
    float* out = (float*)d_out;

    const int N = N_NODES, E = N_EDGES;
    const int* src = ei;
    const int* dst = ei + E;

    size_t o = 0;
    auto alloc = [&](size_t bytes) {
        void* p = (char*)d_ws + o;
        o += (bytes + 255) / 256 * 256;
        return p;
    };
    int*           pcnt   = (int*)alloc((size_t)SBLOCKS * NB * 4);
    int*           btot   = (int*)alloc((size_t)NB * 4);
    int*           bbase  = (int*)alloc((size_t)(NB + 1) * 4);
    int*           off    = (int*)alloc((size_t)(N + 1) * 4);
    float*         dinv   = (float*)alloc((size_t)N * 4);
    unsigned int*  pairs  = (unsigned int*)alloc((size_t)E * 4);
    int*           col    = (int*)alloc((size_t)E * 4);
    unsigned char* T      = (unsigned char*)alloc((size_t)N * 64);
    __half*        H      = (__half*)alloc((size_t)N * 64 * 2);
    float*         pooled = (float*)alloc((size_t)N_GRAPHS * 64 * 4);

    // per-call zeroing of atomic targets (ws is not re-poisoned between replays)
    hipMemsetAsync(pooled, 0, (size_t)N_GRAPHS * 64 * 4, stream);

    // CSR build: per-block histogram -> 2-level scan -> scatter -> per-bucket sort
    phist_kernel<<<SBLOCKS, 256, 0, stream>>>(dst, pcnt, E);
    pscanA_kernel<<<NB, 256, 0, stream>>>(pcnt, btot);
    pscanB_kernel<<<1, 512, 0, stream>>>(btot, bbase, off + N, E);
    scatter2_kernel<<<SBLOCKS, 256, 0, stream>>>(src, dst, pcnt, bbase, pairs, E);
    bucket_kernel<<<NB, 256, 0, stream>>>(pairs, bbase, col, off, dinv, N);

    // layer 1: U = fp8(dinv * (x @ W1)) ; H = fp16(relu(dinv * (sum + self) + b1))
    lin_kernel<128, float><<<N / 32, 256, 0, stream>>>(x, W1, dinv, T);
    agg_kernel<true, false><<<(N + 3) / 4, 256, 0, stream>>>(T, off, col, dinv, b1, H, nullptr, nullptr, N);

    // layer 2 (pooling fused into aggregation)
    lin_kernel<64, __half><<<N / 32, 256, 0, stream>>>(H, W2, dinv, T);
    agg_kernel<false, true><<<(N + 3) / 4, 256, 0, stream>>>(T, off, col, dinv, b2, nullptr, pooled, bat, N);

    // head: counts + mean + folded MLP + softmax over graphs
    head_kernel<<<1, 512, 0, stream>>>(pooled, bat, Wl1, bl1, Wl2, bl2, out, N);
}

// Round 8
// 225.707 us; speedup vs baseline: 4.9026x; 1.2694x over previous
//
#include <hip/hip_runtime.h>
#include <hip/hip_fp16.h>
#include <math.h>

#define N_NODES 100000
#define N_EDGES 3200000
#define N_GRAPHS 512

#define BSHIFT 8
#define BSPAN 256                      // nodes per bucket
#define NB 391                         // ceil(N_NODES / BSPAN)
#define SBLK 4096                      // edges per scatter block
#define SBLOCKS ((N_EDGES + SBLK - 1) / SBLK)   // 782
#define SCAN_IT ((SBLOCKS + 255) / 256)         // 4

typedef float floatx2 __attribute__((ext_vector_type(2)));

// ---------- pass 1: per-block bucket histogram -> pcnt[block][bucket] ----------
__global__ __launch_bounds__(256) void phist_kernel(const int* __restrict__ dst,
                                                    int* __restrict__ pcnt, int E) {
    __shared__ int h[NB];
    int tid = threadIdx.x;
    for (int b = tid; b < NB; b += 256) h[b] = 0;
    __syncthreads();
    int base = blockIdx.x * SBLK;
    int end = min(E, base + SBLK);
    for (int e = base + tid; e < end; e += 256)
        atomicAdd(&h[dst[e] >> BSHIFT], 1);
    __syncthreads();
    int* row = pcnt + (size_t)blockIdx.x * NB;
    for (int b = tid; b < NB; b += 256) row[b] = h[b];
}

// ---------- pass 2a: per-bucket scan over blocks (block b handles bucket b) ----------
__global__ __launch_bounds__(256) void pscanA_kernel(int* __restrict__ pcnt,
                                                     int* __restrict__ btot) {
    __shared__ int s[256];
    int b = blockIdx.x, tid = threadIdx.x;
    int v[SCAN_IT];
    int sum = 0;
#pragma unroll
    for (int j = 0; j < SCAN_IT; ++j) {
        int idx = tid * SCAN_IT + j;
        v[j] = (idx < SBLOCKS) ? pcnt[(size_t)idx * NB + b] : 0;
        sum += v[j];
    }
    s[tid] = sum;
    __syncthreads();
    for (int st = 1; st < 256; st <<= 1) {
        int t = (tid >= st) ? s[tid - st] : 0;
        __syncthreads();
        s[tid] += t;
        __syncthreads();
    }
    int run = s[tid] - sum;
#pragma unroll
    for (int j = 0; j < SCAN_IT; ++j) {
        int idx = tid * SCAN_IT + j;
        if (idx < SBLOCKS) pcnt[(size_t)idx * NB + b] = run;
        run += v[j];
    }
    if (tid == 255) btot[b] = run;
}

// ---------- pass 2b: scan bucket totals -> bbase ----------
__global__ __launch_bounds__(512) void pscanB_kernel(const int* __restrict__ btot,
                                                     int* __restrict__ bbase,
                                                     int* __restrict__ offN, int E) {
    __shared__ int s[512];
    int tid = threadIdx.x;
    int v = (tid < NB) ? btot[tid] : 0;
    s[tid] = v;
    __syncthreads();
    for (int st = 1; st < 512; st <<= 1) {
        int t = (tid >= st) ? s[tid - st] : 0;
        __syncthreads();
        s[tid] += t;
        __syncthreads();
    }
    int excl = s[tid] - v;
    if (tid < NB) bbase[tid] = excl;
    if (tid == NB - 1) bbase[NB] = excl + v;
    if (tid == 0) *offN = E;
}

// ---------- pass 3: scatter edges into bucket segments (packed 32-bit) ----------
__global__ __launch_bounds__(256) void scatter2_kernel(const int* __restrict__ src,
                                                       const int* __restrict__ dst,
                                                       const int* __restrict__ pbase,
                                                       const int* __restrict__ bbase,
                                                       unsigned int* __restrict__ pairs, int E) {
    __shared__ int hrank[NB];
    __shared__ int hb[NB];
    int tid = threadIdx.x;
    const int* row = pbase + (size_t)blockIdx.x * NB;
    for (int b = tid; b < NB; b += 256) { hrank[b] = 0; hb[b] = row[b] + bbase[b]; }
    __syncthreads();
    int base = blockIdx.x * SBLK;
    int end = min(E, base + SBLK);
    for (int e = base + tid; e < end; e += 256) {
        int d = dst[e];
        int b = d >> BSHIFT;
        int rk = atomicAdd(&hrank[b], 1);
        pairs[hb[b] + rk] = ((unsigned int)src[e] << BSHIFT) | (unsigned int)(d & (BSPAN - 1));
    }
}

// ---------- pass 4: per-bucket fine sort -> col (src<<3 byte offsets), off, dinv ----------
__global__ __launch_bounds__(256) void bucket_kernel(const unsigned int* __restrict__ pairs,
                                                     const int* __restrict__ bbase,
                                                     int* __restrict__ col,
                                                     int* __restrict__ off,
                                                     float* __restrict__ dinv, int N) {
    __shared__ int ncnt[BSPAN];
    __shared__ int nbase[BSPAN];
    __shared__ int a[BSPAN];
    int b = blockIdx.x, tid = threadIdx.x;
    int base = bbase[b];
    int cntb = bbase[b + 1] - base;
    int n0 = b << BSHIFT;
    int nn = min(BSPAN, N - n0);
    ncnt[tid] = 0;
    __syncthreads();
    for (int i = tid; i < cntb; i += 256)
        atomicAdd(&ncnt[pairs[base + i] & (BSPAN - 1)], 1);
    __syncthreads();
    int v = ncnt[tid];
    a[tid] = v;
    __syncthreads();
    for (int st = 1; st < 256; st <<= 1) {
        int t = (tid >= st) ? a[tid - st] : 0;
        __syncthreads();
        a[tid] += t;
        __syncthreads();
    }
    nbase[tid] = a[tid] - v;
    if (tid < nn) {
        off[n0 + tid] = base + nbase[tid];
        dinv[n0 + tid] = rsqrtf((float)(v + 1));   // +1 self loop
    }
    ncnt[tid] = 0;   // reuse as cursor
    __syncthreads();
    for (int i = tid; i < cntb; i += 256) {
        unsigned int p = pairs[base + i];
        int dl = p & (BSPAN - 1);
        int pos = base + nbase[dl] + atomicAdd(&ncnt[dl], 1);
        col[pos] = (int)(p >> BSHIFT) << 3;   // byte offset into qz (float2 rows)
    }
}

// ---------- fold head: Wz = W2 @ (Wl1@Wl2)  [64x2], zc = b2@Weff + bl1@Wl2 + bl2 ----------
__global__ __launch_bounds__(128) void wz_kernel(const float* __restrict__ W2,
                                                 const float* __restrict__ b2,
                                                 const float* __restrict__ Wl1,
                                                 const float* __restrict__ bl1,
                                                 const float* __restrict__ Wl2,
                                                 const float* __restrict__ bl2,
                                                 float* __restrict__ Wz,
                                                 float* __restrict__ zc) {
    __shared__ float Weff[64 * 2];
    int tid = threadIdx.x;
    {
        int c = tid >> 1, j = tid & 1;
        float s = 0.f;
        for (int k = 0; k < 32; ++k) s += Wl1[c * 32 + k] * Wl2[k * 2 + j];
        Weff[c * 2 + j] = s;
    }
    __syncthreads();
    {
        int i = tid >> 1, j = tid & 1;
        float s = 0.f;
        for (int c = 0; c < 64; ++c) s += W2[i * 64 + c] * Weff[c * 2 + j];
        Wz[i * 2 + j] = s;
    }
    if (tid < 2) {
        float s = bl2[tid];
        for (int k = 0; k < 32; ++k) s += bl1[k] * Wl2[k * 2 + tid];
        for (int c = 0; c < 64; ++c) s += b2[c] * Weff[c * 2 + tid];
        zc[tid] = s;
    }
}

// ---------- dense linear: U[n,64] = fp8(dinv[n] * (X[n,K] @ W[K,64])) ----------
template <int K>
__global__ __launch_bounds__(256) void lin_kernel(const float* __restrict__ X,
                                                  const float* __restrict__ W,
                                                  const float* __restrict__ rs,
                                                  unsigned char* __restrict__ U) {
    __shared__ float Ws[K * 64];
    __shared__ float Xs[32 * K];
    int tid = threadIdx.x;
    for (int i = tid * 4; i < K * 64; i += 256 * 4)
        *reinterpret_cast<float4*>(&Ws[i]) = *reinterpret_cast<const float4*>(&W[i]);
    int row0 = blockIdx.x * 32;
    const float* Xbase = X + (size_t)row0 * K;
    for (int i = tid * 4; i < 32 * K; i += 256 * 4)
        *reinterpret_cast<float4*>(&Xs[i]) = *reinterpret_cast<const float4*>(&Xbase[i]);
    __syncthreads();

    int wid = tid >> 6, lane = tid & 63;
    int rbase = wid * 8;
    float acc[8];
#pragma unroll
    for (int r = 0; r < 8; ++r) acc[r] = 0.f;

    for (int k4 = 0; k4 < K / 4; ++k4) {
        float w0 = Ws[(k4 * 4 + 0) * 64 + lane];
        float w1 = Ws[(k4 * 4 + 1) * 64 + lane];
        float w2 = Ws[(k4 * 4 + 2) * 64 + lane];
        float w3 = Ws[(k4 * 4 + 3) * 64 + lane];
#pragma unroll
        for (int r = 0; r < 8; ++r) {
            float4 xv = *reinterpret_cast<const float4*>(&Xs[(rbase + r) * K + k4 * 4]);
            acc[r] += xv.x * w0 + xv.y * w1 + xv.z * w2 + xv.w * w3;
        }
    }
#pragma unroll
    for (int r = 0; r < 8; ++r) {
        int row = row0 + rbase + r;
        float v = acc[r] * rs[row];
        int pk = __builtin_amdgcn_cvt_pk_fp8_f32(v, v, 0, false);
        U[(size_t)row * 64 + lane] = (unsigned char)(pk & 0xff);
    }
}

// ---------- agg1: wave = node, 8 lanes/edge x 8 slots, fp8 gathers, f32 accumulate.
// Epilogue: relu(dinv*(sum+self)+b1), fold @Wz, write qz[node] (float2). ----------
#define ACC8(a)                                                                  \
    {                                                                            \
        floatx2 f_;                                                              \
        f_ = __builtin_amdgcn_cvt_pk_f32_fp8((int)(a).x, false);                 \
        acc[0] += f_.x; acc[1] += f_.y;                                          \
        f_ = __builtin_amdgcn_cvt_pk_f32_fp8((int)(a).x, true);                  \
        acc[2] += f_.x; acc[3] += f_.y;                                          \
        f_ = __builtin_amdgcn_cvt_pk_f32_fp8((int)(a).y, false);                 \
        acc[4] += f_.x; acc[5] += f_.y;                                          \
        f_ = __builtin_amdgcn_cvt_pk_f32_fp8((int)(a).y, true);                  \
        acc[6] += f_.x; acc[7] += f_.y;                                          \
    }

__global__ __launch_bounds__(256) void agg1_kernel(const unsigned char* __restrict__ u,
                                                   const int* __restrict__ off,
                                                   const int* __restrict__ col,
                                                   const float* __restrict__ dinv,
                                                   const float* __restrict__ bias,
                                                   const float* __restrict__ Wz,
                                                   float2* __restrict__ qz, int n) {
    __shared__ float Wzs[128];
    int tid = threadIdx.x;
    if (tid < 128) Wzs[tid] = Wz[tid];
    __syncthreads();

    int wid = tid >> 6, lane = tid & 63;
    int node = blockIdx.x * 4 + wid;
    if (node >= n) return;
    int r = lane >> 3, c = lane & 7;   // edge slot, feat group
    unsigned int c8 = (unsigned int)c * 8;

    int beg = off[node], end = off[node + 1];
    float acc[8];
#pragma unroll
    for (int j = 0; j < 8; ++j) acc[j] = 0.f;
    int e = beg + r;
    while (e + 24 < end) {
        unsigned int v0 = ((unsigned int)col[e]      << 3) + c8;
        unsigned int v1 = ((unsigned int)col[e + 8]  << 3) + c8;
        unsigned int v2 = ((unsigned int)col[e + 16] << 3) + c8;
        unsigned int v3 = ((unsigned int)col[e + 24] << 3) + c8;
        uint2 a0 = *reinterpret_cast<const uint2*>(u + v0);
        uint2 a1 = *reinterpret_cast<const uint2*>(u + v1);
        uint2 a2 = *reinterpret_cast<const uint2*>(u + v2);
        uint2 a3 = *reinterpret_cast<const uint2*>(u + v3);
        ACC8(a0); ACC8(a1); ACC8(a2); ACC8(a3);
        e += 32;
    }
    while (e + 8 < end) {
        unsigned int v0 = ((unsigned int)col[e]     << 3) + c8;
        unsigned int v1 = ((unsigned int)col[e + 8] << 3) + c8;
        uint2 a0 = *reinterpret_cast<const uint2*>(u + v0);
        uint2 a1 = *reinterpret_cast<const uint2*>(u + v1);
        ACC8(a0); ACC8(a1);
        e += 16;
    }
    if (e < end) {
        unsigned int v0 = ((unsigned int)col[e] << 3) + c8;
        uint2 a0 = *reinterpret_cast<const uint2*>(u + v0);
        ACC8(a0);
    }
#pragma unroll
    for (int m = 8; m <= 32; m <<= 1) {
#pragma unroll
        for (int j = 0; j < 8; ++j) acc[j] += __shfl_xor(acc[j], m);
    }
    // epilogue in lanes 0..7 (r==0): o = relu(di*(acc+self)+b), fold @Wz
    unsigned int vs = ((unsigned int)node << 6) + c8;
    uint2 sfr = *reinterpret_cast<const uint2*>(u + vs);
    ACC8(sfr);
    float di = dinv[node];
    float4 b0 = *reinterpret_cast<const float4*>(&bias[c * 8]);
    float4 b1 = *reinterpret_cast<const float4*>(&bias[c * 8 + 4]);
    float o[8];
#pragma unroll
    for (int j = 0; j < 8; ++j) o[j] = di * acc[j];
    o[0] += b0.x; o[1] += b0.y; o[2] += b0.z; o[3] += b0.w;
    o[4] += b1.x; o[5] += b1.y; o[6] += b1.z; o[7] += b1.w;
#pragma unroll
    for (int j = 0; j < 8; ++j) o[j] = fmaxf(o[j], 0.f);
    float p0 = 0.f, p1 = 0.f;
#pragma unroll
    for (int j = 0; j < 8; ++j) {
        p0 += o[j] * Wzs[(c * 8 + j) * 2 + 0];
        p1 += o[j] * Wzs[(c * 8 + j) * 2 + 1];
    }
#pragma unroll
    for (int m = 1; m <= 4; m <<= 1) {
        p0 += __shfl_xor(p0, m);
        p1 += __shfl_xor(p1, m);
    }
    if (lane == 0) qz[node] = make_float2(p0 * di, p1 * di);
}

// ---------- agg2q: 16 lanes/node x 4 nodes/wave, float2 gathers from qz,
// fused segmented pooling into pooled2[g*2+j] ----------
__global__ __launch_bounds__(256) void agg2q_kernel(const float2* __restrict__ qz,
                                                    const int* __restrict__ off,
                                                    const int* __restrict__ col,
                                                    const float* __restrict__ dinv,
                                                    float* __restrict__ pooled2,
                                                    const int* __restrict__ batch, int n) {
    __shared__ float2 sh[16];
    __shared__ int sg[16];
    int tid = threadIdx.x;
    int wid = tid >> 6, lane = tid & 63;
    int sub = lane >> 4, slot = lane & 15;
    int li = wid * 4 + sub;                 // 0..15 node slot in block
    int node = blockIdx.x * 16 + li;
    bool valid = node < n;

    float ax = 0.f, ay = 0.f;
    if (valid) {
        int beg = off[node], end = off[node + 1];
        const char* qb = (const char*)qz;
        int e = beg + slot;
        while (e + 16 < end) {
            float2 v0 = *reinterpret_cast<const float2*>(qb + (unsigned int)col[e]);
            float2 v1 = *reinterpret_cast<const float2*>(qb + (unsigned int)col[e + 16]);
            ax += v0.x + v1.x; ay += v0.y + v1.y;
            e += 32;
        }
        if (e < end) {
            float2 v0 = *reinterpret_cast<const float2*>(qb + (unsigned int)col[e]);
            ax += v0.x; ay += v0.y;
        }
    }
#pragma unroll
    for (int m = 1; m <= 8; m <<= 1) {
        ax += __shfl_xor(ax, m);
        ay += __shfl_xor(ay, m);
    }
    if (slot == 0) {
        if (valid) {
            float2 self = qz[node];
            float di = dinv[node];
            sh[li] = make_float2(di * (ax + self.x), di * (ay + self.y));
            sg[li] = batch[node];
        } else {
            sh[li] = make_float2(0.f, 0.f);
            sg[li] = -1;
        }
    }
    __syncthreads();
    if (tid < 2) {
        float s = 0.f;
        int gp = -1;
        for (int w = 0; w < 16; ++w) {
            int g = sg[w];
            if (g < 0) continue;
            if (g != gp) {
                if (gp >= 0) atomicAdd(&pooled2[gp * 2 + tid], s);
                s = 0.f;
                gp = g;
            }
            s += (tid == 0) ? sh[w].x : sh[w].y;
        }
        if (gp >= 0) atomicAdd(&pooled2[gp * 2 + tid], s);
    }
}

// ---------- head: counts via binary search, z = pooled2/cnt + zc, softmax over graphs ----------
__global__ __launch_bounds__(512) void head_kernel(const float* __restrict__ pooled2,
                                                   const int* __restrict__ batch,
                                                   const float* __restrict__ zc,
                                                   float* __restrict__ out, int N) {
    __shared__ float red[512];
    int tid = threadIdx.x;
    int g = tid;
    auto lb = [&](int key) {
        int l = 0, r = N;
        while (l < r) { int m = (l + r) >> 1; if (batch[m] < key) l = m + 1; else r = m; }
        return l;
    };
    int cnt = lb(g + 1) - lb(g);
    float cn = fmaxf((float)cnt, 1.f);
    float z0 = pooled2[g * 2 + 0] / cn + zc[0];
    float z1 = pooled2[g * 2 + 1] / cn + zc[1];

    red[tid] = z0; __syncthreads();
    for (int s = 256; s > 0; s >>= 1) { if (tid < s) red[tid] = fmaxf(red[tid], red[tid + s]); __syncthreads(); }
    float m0 = red[0]; __syncthreads();
    float e0 = expf(z0 - m0);
    red[tid] = e0; __syncthreads();
    for (int s = 256; s > 0; s >>= 1) { if (tid < s) red[tid] += red[tid + s]; __syncthreads(); }
    float s0 = red[0]; __syncthreads();
    out[g * 2 + 0] = e0 / s0;

    red[tid] = z1; __syncthreads();
    for (int s = 256; s > 0; s >>= 1) { if (tid < s) red[tid] = fmaxf(red[tid], red[tid + s]); __syncthreads(); }
    float m1 = red[0]; __syncthreads();
    float e1 = expf(z1 - m1);
    red[tid] = e1; __syncthreads();
    for (int s = 256; s > 0; s >>= 1) { if (tid < s) red[tid] += red[tid + s]; __syncthreads(); }
    float s1 = red[0]; __syncthreads();
    out[g * 2 + 1] = e1 / s1;
}

// ---------- launch ----------
extern "C" void kernel_launch(void* const* d_in, const int* in_sizes, int n_in,
                              void* d_out, int out_size, void* d_ws, size_t ws_size,
                              hipStream_t stream) {
    const float* x   = (const float*)d_in[0];
    const int*   ei  = (const int*)d_in[1];
    const int*   bat = (const int*)d_in[2];
    const float* W1  = (const float*)d_in[3];
    const float* b1  = (const float*)d_in[4];
    const float* W2  = (const float*)d_in[5];
    const float* b2  = (const float*)d_in[6];
    const float* Wl1 = (const float*)d_in[7];
    const float* bl1 = (const float*)d_in[8];
    const float* Wl2 = (const float*)d_in[9];
    const float* bl2 = (const float*)d_in[10];
    float* out = (float*)d_out;

    const int N = N_NODES, E = N_EDGES;
    const int* src = ei;
    const int* dst = ei + E;

    size_t o = 0;
    auto alloc = [&](size_t bytes) {
        void* p = (char*)d_ws + o;
        o += (bytes + 255) / 256 * 256;
        return p;
    };
    int*           pcnt    = (int*)alloc((size_t)SBLOCKS * NB * 4);
    int*           btot    = (int*)alloc((size_t)NB * 4);
    int*           bbase   = (int*)alloc((size_t)(NB + 1) * 4);
    int*           off     = (int*)alloc((size_t)(N + 1) * 4);
    float*         dinv    = (float*)alloc((size_t)N * 4);
    unsigned int*  pairs   = (unsigned int*)alloc((size_t)E * 4);
    int*           col     = (int*)alloc((size_t)E * 4);
    unsigned char* T       = (unsigned char*)alloc((size_t)N * 64);
    float2*        qz      = (float2*)alloc((size_t)N * 8);
    float*         Wz      = (float*)alloc(128 * 4);
    float*         zc      = (float*)alloc(2 * 4);
    float*         pooled2 = (float*)alloc((size_t)N_GRAPHS * 2 * 4);

    // per-call zeroing of atomic targets (ws is not re-poisoned between replays)
    hipMemsetAsync(pooled2, 0, (size_t)N_GRAPHS * 2 * 4, stream);

    // CSR build: per-block histogram -> 2-level scan -> scatter -> per-bucket sort
    phist_kernel<<<SBLOCKS, 256, 0, stream>>>(dst, pcnt, E);
    pscanA_kernel<<<NB, 256, 0, stream>>>(pcnt, btot);
    pscanB_kernel<<<1, 512, 0, stream>>>(btot, bbase, off + N, E);
    scatter2_kernel<<<SBLOCKS, 256, 0, stream>>>(src, dst, pcnt, bbase, pairs, E);
    bucket_kernel<<<NB, 256, 0, stream>>>(pairs, bbase, col, off, dinv, N);

    // fold W2 @ Wl1 @ Wl2 -> Wz [64x2], constant zc [2]
    wz_kernel<<<1, 128, 0, stream>>>(W2, b2, Wl1, bl1, Wl2, bl2, Wz, zc);

    // layer 1: U = fp8(dinv * (x @ W1)) ; qz = dinv * relu(dinv*(sum+self)+b1) @ Wz
    lin_kernel<128><<<N / 32, 256, 0, stream>>>(x, W1, dinv, T);
    agg1_kernel<<<(N + 3) / 4, 256, 0, stream>>>(T, off, col, dinv, b1, Wz, qz, N);

    // layer 2 collapsed to 2 features + fused pooling
    agg2q_kernel<<<(N + 15) / 16, 256, 0, stream>>>(qz, off, col, dinv, pooled2, bat, N);

    // head: counts + mean + const + softmax over graphs
    head_kernel<<<1, 512, 0, stream>>>(pooled2, bat, zc, out, N);
}

// Round 9
// 216.800 us; speedup vs baseline: 5.1040x; 1.0411x over previous
//
#include <hip/hip_runtime.h>
#include <hip/hip_fp16.h>
#include <math.h>

#define N_NODES 100000
#define N_EDGES 3200000
#define N_GRAPHS 512

#define BSHIFT 8
#define BSPAN 256                      // nodes per bucket
#define NB 391                         // ceil(N_NODES / BSPAN)
#define SBLK 4096                      // edges per scatter block
#define SBLOCKS ((N_EDGES + SBLK - 1) / SBLK)   // 782
#define SCAN_IT ((SBLOCKS + 255) / 256)         // 4

typedef float floatx2 __attribute__((ext_vector_type(2)));

// ---------- pass 1: per-block bucket histogram -> pcnt[block][bucket] ----------
__global__ __launch_bounds__(256) void phist_kernel(const int* __restrict__ dst,
                                                    int* __restrict__ pcnt, int E) {
    __shared__ int h[NB];
    int tid = threadIdx.x;
    for (int b = tid; b < NB; b += 256) h[b] = 0;
    __syncthreads();
    int base = blockIdx.x * SBLK;
    int end = min(E, base + SBLK);
    int e = base + tid * 4;
    for (; e + 3 < end; e += 1024) {
        int4 d4 = *reinterpret_cast<const int4*>(&dst[e]);
        atomicAdd(&h[d4.x >> BSHIFT], 1);
        atomicAdd(&h[d4.y >> BSHIFT], 1);
        atomicAdd(&h[d4.z >> BSHIFT], 1);
        atomicAdd(&h[d4.w >> BSHIFT], 1);
    }
    for (; e < end; ++e) atomicAdd(&h[dst[e] >> BSHIFT], 1);
    __syncthreads();
    int* row = pcnt + (size_t)blockIdx.x * NB;
    for (int b = tid; b < NB; b += 256) row[b] = h[b];
}

// ---------- pass 2a: per-bucket scan over blocks (block b handles bucket b) ----------
__global__ __launch_bounds__(256) void pscanA_kernel(int* __restrict__ pcnt,
                                                     int* __restrict__ btot) {
    __shared__ int s[256];
    int b = blockIdx.x, tid = threadIdx.x;
    int v[SCAN_IT];
    int sum = 0;
#pragma unroll
    for (int j = 0; j < SCAN_IT; ++j) {
        int idx = tid * SCAN_IT + j;
        v[j] = (idx < SBLOCKS) ? pcnt[(size_t)idx * NB + b] : 0;
        sum += v[j];
    }
    s[tid] = sum;
    __syncthreads();
    for (int st = 1; st < 256; st <<= 1) {
        int t = (tid >= st) ? s[tid - st] : 0;
        __syncthreads();
        s[tid] += t;
        __syncthreads();
    }
    int run = s[tid] - sum;
#pragma unroll
    for (int j = 0; j < SCAN_IT; ++j) {
        int idx = tid * SCAN_IT + j;
        if (idx < SBLOCKS) pcnt[(size_t)idx * NB + b] = run;
        run += v[j];
    }
    if (tid == 255) btot[b] = run;
}

// ---------- pass 2b: scan bucket totals -> bbase ----------
__global__ __launch_bounds__(512) void pscanB_kernel(const int* __restrict__ btot,
                                                     int* __restrict__ bbase,
                                                     int* __restrict__ offN, int E) {
    __shared__ int s[512];
    int tid = threadIdx.x;
    int v = (tid < NB) ? btot[tid] : 0;
    s[tid] = v;
    __syncthreads();
    for (int st = 1; st < 512; st <<= 1) {
        int t = (tid >= st) ? s[tid - st] : 0;
        __syncthreads();
        s[tid] += t;
        __syncthreads();
    }
    int excl = s[tid] - v;
    if (tid < NB) bbase[tid] = excl;
    if (tid == NB - 1) bbase[NB] = excl + v;
    if (tid == 0) *offN = E;
}

// ---------- pass 3: scatter edges into bucket segments (packed 32-bit) ----------
__global__ __launch_bounds__(256) void scatter2_kernel(const int* __restrict__ src,
                                                       const int* __restrict__ dst,
                                                       const int* __restrict__ pbase,
                                                       const int* __restrict__ bbase,
                                                       unsigned int* __restrict__ pairs, int E) {
    __shared__ int hrank[NB];
    __shared__ int hb[NB];
    int tid = threadIdx.x;
    const int* row = pbase + (size_t)blockIdx.x * NB;
    for (int b = tid; b < NB; b += 256) { hrank[b] = 0; hb[b] = row[b] + bbase[b]; }
    __syncthreads();
    int base = blockIdx.x * SBLK;
    int end = min(E, base + SBLK);
    int e = base + tid * 4;
    for (; e + 3 < end; e += 1024) {
        int4 d4 = *reinterpret_cast<const int4*>(&dst[e]);
        int4 s4 = *reinterpret_cast<const int4*>(&src[e]);
        int b0 = d4.x >> BSHIFT, b1 = d4.y >> BSHIFT, b2 = d4.z >> BSHIFT, b3 = d4.w >> BSHIFT;
        int r0 = atomicAdd(&hrank[b0], 1);
        int r1 = atomicAdd(&hrank[b1], 1);
        int r2 = atomicAdd(&hrank[b2], 1);
        int r3 = atomicAdd(&hrank[b3], 1);
        pairs[hb[b0] + r0] = ((unsigned int)s4.x << BSHIFT) | (unsigned int)(d4.x & (BSPAN - 1));
        pairs[hb[b1] + r1] = ((unsigned int)s4.y << BSHIFT) | (unsigned int)(d4.y & (BSPAN - 1));
        pairs[hb[b2] + r2] = ((unsigned int)s4.z << BSHIFT) | (unsigned int)(d4.z & (BSPAN - 1));
        pairs[hb[b3] + r3] = ((unsigned int)s4.w << BSHIFT) | (unsigned int)(d4.w & (BSPAN - 1));
    }
    for (; e < end; ++e) {
        int d = dst[e];
        int b = d >> BSHIFT;
        int rk = atomicAdd(&hrank[b], 1);
        pairs[hb[b] + rk] = ((unsigned int)src[e] << BSHIFT) | (unsigned int)(d & (BSPAN - 1));
    }
}

// ---------- pass 4: per-bucket fine sort -> col (src<<3 byte offsets), off, dinv ----------
__global__ __launch_bounds__(256) void bucket_kernel(const unsigned int* __restrict__ pairs,
                                                     const int* __restrict__ bbase,
                                                     int* __restrict__ col,
                                                     int* __restrict__ off,
                                                     float* __restrict__ dinv, int N) {
    __shared__ int ncnt[BSPAN];
    __shared__ int nbase[BSPAN];
    __shared__ int a[BSPAN];
    int b = blockIdx.x, tid = threadIdx.x;
    int base = bbase[b];
    int cntb = bbase[b + 1] - base;
    int n0 = b << BSHIFT;
    int nn = min(BSPAN, N - n0);
    ncnt[tid] = 0;
    __syncthreads();
    for (int i = tid; i < cntb; i += 256)
        atomicAdd(&ncnt[pairs[base + i] & (BSPAN - 1)], 1);
    __syncthreads();
    int v = ncnt[tid];
    a[tid] = v;
    __syncthreads();
    for (int st = 1; st < 256; st <<= 1) {
        int t = (tid >= st) ? a[tid - st] : 0;
        __syncthreads();
        a[tid] += t;
        __syncthreads();
    }
    nbase[tid] = a[tid] - v;
    if (tid < nn) {
        off[n0 + tid] = base + nbase[tid];
        dinv[n0 + tid] = rsqrtf((float)(v + 1));   // +1 self loop
    }
    ncnt[tid] = 0;   // reuse as cursor
    __syncthreads();
    for (int i = tid; i < cntb; i += 256) {
        unsigned int p = pairs[base + i];
        int dl = p & (BSPAN - 1);
        int pos = base + nbase[dl] + atomicAdd(&ncnt[dl], 1);
        col[pos] = (int)(p >> BSHIFT) << 3;   // byte offset into qz (float2 rows)
    }
}

// ---------- fold head: Wz = W2 @ (Wl1@Wl2)  [64x2], zc = b2@Weff + bl1@Wl2 + bl2 ----------
__global__ __launch_bounds__(128) void wz_kernel(const float* __restrict__ W2,
                                                 const float* __restrict__ b2,
                                                 const float* __restrict__ Wl1,
                                                 const float* __restrict__ bl1,
                                                 const float* __restrict__ Wl2,
                                                 const float* __restrict__ bl2,
                                                 float* __restrict__ Wz,
                                                 float* __restrict__ zc) {
    __shared__ float Weff[64 * 2];
    int tid = threadIdx.x;
    {
        int c = tid >> 1, j = tid & 1;
        float s = 0.f;
        for (int k = 0; k < 32; ++k) s += Wl1[c * 32 + k] * Wl2[k * 2 + j];
        Weff[c * 2 + j] = s;
    }
    __syncthreads();
    {
        int i = tid >> 1, j = tid & 1;
        float s = 0.f;
        for (int c = 0; c < 64; ++c) s += W2[i * 64 + c] * Weff[c * 2 + j];
        Wz[i * 2 + j] = s;
    }
    if (tid < 2) {
        float s = bl2[tid];
        for (int k = 0; k < 32; ++k) s += bl1[k] * Wl2[k * 2 + tid];
        for (int c = 0; c < 64; ++c) s += b2[c] * Weff[c * 2 + tid];
        zc[tid] = s;
    }
}

// ---------- dense linear: U[n,64] = fp8(dinv[n] * (X[n,K] @ W[K,64])) ----------
template <int K>
__global__ __launch_bounds__(256) void lin_kernel(const float* __restrict__ X,
                                                  const float* __restrict__ W,
                                                  const float* __restrict__ rs,
                                                  unsigned char* __restrict__ U) {
    __shared__ float Ws[K * 64];
    __shared__ float Xs[32 * K];
    int tid = threadIdx.x;
    for (int i = tid * 4; i < K * 64; i += 256 * 4)
        *reinterpret_cast<float4*>(&Ws[i]) = *reinterpret_cast<const float4*>(&W[i]);
    int row0 = blockIdx.x * 32;
    const float* Xbase = X + (size_t)row0 * K;
    for (int i = tid * 4; i < 32 * K; i += 256 * 4)
        *reinterpret_cast<float4*>(&Xs[i]) = *reinterpret_cast<const float4*>(&Xbase[i]);
    __syncthreads();

    int wid = tid >> 6, lane = tid & 63;
    int rbase = wid * 8;
    float acc[8];
#pragma unroll
    for (int r = 0; r < 8; ++r) acc[r] = 0.f;

    for (int k4 = 0; k4 < K / 4; ++k4) {
        float w0 = Ws[(k4 * 4 + 0) * 64 + lane];
        float w1 = Ws[(k4 * 4 + 1) * 64 + lane];
        float w2 = Ws[(k4 * 4 + 2) * 64 + lane];
        float w3 = Ws[(k4 * 4 + 3) * 64 + lane];
#pragma unroll
        for (int r = 0; r < 8; ++r) {
            float4 xv = *reinterpret_cast<const float4*>(&Xs[(rbase + r) * K + k4 * 4]);
            acc[r] += xv.x * w0 + xv.y * w1 + xv.z * w2 + xv.w * w3;
        }
    }
#pragma unroll
    for (int r = 0; r < 8; ++r) {
        int row = row0 + rbase + r;
        float v = acc[r] * rs[row];
        int pk = __builtin_amdgcn_cvt_pk_fp8_f32(v, v, 0, false);
        U[(size_t)row * 64 + lane] = (unsigned char)(pk & 0xff);
    }
}

// ---------- agg1: wave = node, 8 lanes/edge x 8 slots, fp8 gathers, packed f32 accum.
// Epilogue (r==0 lanes only): relu(dinv*(sum+self)+b1), fold @Wz, write qz (float2). ----------
#define ACC8(a)                                                                  \
    {                                                                            \
        acc2[0] += __builtin_amdgcn_cvt_pk_f32_fp8((int)(a).x, false);           \
        acc2[1] += __builtin_amdgcn_cvt_pk_f32_fp8((int)(a).x, true);            \
        acc2[2] += __builtin_amdgcn_cvt_pk_f32_fp8((int)(a).y, false);           \
        acc2[3] += __builtin_amdgcn_cvt_pk_f32_fp8((int)(a).y, true);            \
    }

__global__ __launch_bounds__(256) void agg1_kernel(const unsigned char* __restrict__ u,
                                                   const int* __restrict__ off,
                                                   const int* __restrict__ col,
                                                   const float* __restrict__ dinv,
                                                   const float* __restrict__ bias,
                                                   const float* __restrict__ Wz,
                                                   float2* __restrict__ qz, int n) {
    __shared__ float Wz0s[64];
    __shared__ float Wz1s[64];
    int tid = threadIdx.x;
    if (tid < 64) Wz0s[tid] = Wz[tid * 2];
    else if (tid < 128) Wz1s[tid - 64] = Wz[(tid - 64) * 2 + 1];
    __syncthreads();

    int wid = tid >> 6, lane = tid & 63;
    int node = blockIdx.x * 4 + wid;
    if (node >= n) return;
    int r = lane >> 3, c = lane & 7;   // edge slot, feat group
    unsigned int c8 = (unsigned int)c * 8;

    int beg = off[node], end = off[node + 1];
    floatx2 acc2[4];
#pragma unroll
    for (int j = 0; j < 4; ++j) acc2[j] = (floatx2)(0.f);
    int e = beg + r;
    while (e + 24 < end) {
        unsigned int v0 = ((unsigned int)col[e]      << 3) + c8;
        unsigned int v1 = ((unsigned int)col[e + 8]  << 3) + c8;
        unsigned int v2 = ((unsigned int)col[e + 16] << 3) + c8;
        unsigned int v3 = ((unsigned int)col[e + 24] << 3) + c8;
        uint2 a0 = *reinterpret_cast<const uint2*>(u + v0);
        uint2 a1 = *reinterpret_cast<const uint2*>(u + v1);
        uint2 a2 = *reinterpret_cast<const uint2*>(u + v2);
        uint2 a3 = *reinterpret_cast<const uint2*>(u + v3);
        ACC8(a0); ACC8(a1); ACC8(a2); ACC8(a3);
        e += 32;
    }
    while (e + 8 < end) {
        unsigned int v0 = ((unsigned int)col[e]     << 3) + c8;
        unsigned int v1 = ((unsigned int)col[e + 8] << 3) + c8;
        uint2 a0 = *reinterpret_cast<const uint2*>(u + v0);
        uint2 a1 = *reinterpret_cast<const uint2*>(u + v1);
        ACC8(a0); ACC8(a1);
        e += 16;
    }
    if (e < end) {
        unsigned int v0 = ((unsigned int)col[e] << 3) + c8;
        uint2 a0 = *reinterpret_cast<const uint2*>(u + v0);
        ACC8(a0);
    }
    // reduce across the 8 edge-slot groups (lanes differing in bits 3..5)
#pragma unroll
    for (int m = 8; m <= 32; m <<= 1) {
#pragma unroll
        for (int j = 0; j < 4; ++j) {
            acc2[j].x += __shfl_xor(acc2[j].x, m);
            acc2[j].y += __shfl_xor(acc2[j].y, m);
        }
    }
    if (r == 0) {
        // epilogue: lanes 0..7 only
        unsigned int vs = ((unsigned int)node << 6) + c8;
        uint2 sfr = *reinterpret_cast<const uint2*>(u + vs);
        ACC8(sfr);   // add self row
        float di = dinv[node];
        float4 b0 = *reinterpret_cast<const float4*>(&bias[c * 8]);
        float4 b1 = *reinterpret_cast<const float4*>(&bias[c * 8 + 4]);
        float o[8];
#pragma unroll
        for (int j = 0; j < 4; ++j) {
            o[2 * j]     = di * acc2[j].x;
            o[2 * j + 1] = di * acc2[j].y;
        }
        o[0] += b0.x; o[1] += b0.y; o[2] += b0.z; o[3] += b0.w;
        o[4] += b1.x; o[5] += b1.y; o[6] += b1.z; o[7] += b1.w;
#pragma unroll
        for (int j = 0; j < 8; ++j) o[j] = fmaxf(o[j], 0.f);
        float p0 = 0.f, p1 = 0.f;
#pragma unroll
        for (int j = 0; j < 8; ++j) {
            p0 += o[j] * Wz0s[c * 8 + j];
            p1 += o[j] * Wz1s[c * 8 + j];
        }
#pragma unroll
        for (int m = 1; m <= 4; m <<= 1) {
            p0 += __shfl_xor(p0, m);
            p1 += __shfl_xor(p1, m);
        }
        if (lane == 0) qz[node] = make_float2(p0 * di, p1 * di);
    }
}

// ---------- agg2q: 16 lanes/node x 4 nodes/wave, float2 gathers from qz,
// fused segmented pooling into pooled2[g*2+j] ----------
__global__ __launch_bounds__(256) void agg2q_kernel(const float2* __restrict__ qz,
                                                    const int* __restrict__ off,
                                                    const int* __restrict__ col,
                                                    const float* __restrict__ dinv,
                                                    float* __restrict__ pooled2,
                                                    const int* __restrict__ batch, int n) {
    __shared__ float2 sh[16];
    __shared__ int sg[16];
    int tid = threadIdx.x;
    int wid = tid >> 6, lane = tid & 63;
    int sub = lane >> 4, slot = lane & 15;
    int li = wid * 4 + sub;                 // 0..15 node slot in block
    int node = blockIdx.x * 16 + li;
    bool valid = node < n;

    float ax = 0.f, ay = 0.f;
    if (valid) {
        int beg = off[node], end = off[node + 1];
        const char* qb = (const char*)qz;
        int e = beg + slot;
        while (e + 16 < end) {
            float2 v0 = *reinterpret_cast<const float2*>(qb + (unsigned int)col[e]);
            float2 v1 = *reinterpret_cast<const float2*>(qb + (unsigned int)col[e + 16]);
            ax += v0.x + v1.x; ay += v0.y + v1.y;
            e += 32;
        }
        if (e < end) {
            float2 v0 = *reinterpret_cast<const float2*>(qb + (unsigned int)col[e]);
            ax += v0.x; ay += v0.y;
        }
    }
#pragma unroll
    for (int m = 1; m <= 8; m <<= 1) {
        ax += __shfl_xor(ax, m);
        ay += __shfl_xor(ay, m);
    }
    if (slot == 0) {
        if (valid) {
            float2 self = qz[node];
            float di = dinv[node];
            sh[li] = make_float2(di * (ax + self.x), di * (ay + self.y));
            sg[li] = batch[node];
        } else {
            sh[li] = make_float2(0.f, 0.f);
            sg[li] = -1;
        }
    }
    __syncthreads();
    if (tid < 2) {
        float s = 0.f;
        int gp = -1;
        for (int w = 0; w < 16; ++w) {
            int g = sg[w];
            if (g < 0) continue;
            if (g != gp) {
                if (gp >= 0) atomicAdd(&pooled2[gp * 2 + tid], s);
                s = 0.f;
                gp = g;
            }
            s += (tid == 0) ? sh[w].x : sh[w].y;
        }
        if (gp >= 0) atomicAdd(&pooled2[gp * 2 + tid], s);
    }
}

// ---------- head: counts via binary search, z = pooled2/cnt + zc, softmax over graphs ----------
__global__ __launch_bounds__(512) void head_kernel(const float* __restrict__ pooled2,
                                                   const int* __restrict__ batch,
                                                   const float* __restrict__ zc,
                                                   float* __restrict__ out, int N) {
    __shared__ float red[512];
    int tid = threadIdx.x;
    int g = tid;
    auto lb = [&](int key) {
        int l = 0, r = N;
        while (l < r) { int m = (l + r) >> 1; if (batch[m] < key) l = m + 1; else r = m; }
        return l;
    };
    int cnt = lb(g + 1) - lb(g);
    float cn = fmaxf((float)cnt, 1.f);
    float z0 = pooled2[g * 2 + 0] / cn + zc[0];
    float z1 = pooled2[g * 2 + 1] / cn + zc[1];

    red[tid] = z0; __syncthreads();
    for (int s = 256; s > 0; s >>= 1) { if (tid < s) red[tid] = fmaxf(red[tid], red[tid + s]); __syncthreads(); }
    float m0 = red[0]; __syncthreads();
    float e0 = expf(z0 - m0);
    red[tid] = e0; __syncthreads();
    for (int s = 256; s > 0; s >>= 1) { if (tid < s) red[tid] += red[tid + s]; __syncthreads(); }
    float s0 = red[0]; __syncthreads();
    out[g * 2 + 0] = e0 / s0;

    red[tid] = z1; __syncthreads();
    for (int s = 256; s > 0; s >>= 1) { if (tid < s) red[tid] = fmaxf(red[tid], red[tid + s]); __syncthreads(); }
    float m1 = red[0]; __syncthreads();
    float e1 = expf(z1 - m1);
    red[tid] = e1; __syncthreads();
    for (int s = 256; s > 0; s >>= 1) { if (tid < s) red[tid] += red[tid + s]; __syncthreads(); }
    float s1 = red[0]; __syncthreads();
    out[g * 2 + 1] = e1 / s1;
}

// ---------- launch ----------
extern "C" void kernel_launch(void* const* d_in, const int* in_sizes, int n_in,
                              void* d_out, int out_size, void* d_ws, size_t ws_size,
                              hipStream_t stream) {
    const float* x   = (const float*)d_in[0];
    const int*   ei  = (const int*)d_in[1];
    const int*   bat = (const int*)d_in[2];
    const float* W1  = (const float*)d_in[3];
    const float* b1  = (const float*)d_in[4];
    const float* W2  = (const float*)d_in[5];
    const float* b2  = (const float*)d_in[6];
    const float* Wl1 = (const float*)d_in[7];
    const float* bl1 = (const float*)d_in[8];
    const float* Wl2 = (const float*)d_in[9];
    const float* bl2 = (const float*)d_in[10];
    float* out = (float*)d_out;

    const int N = N_NODES, E = N_EDGES;
    const int* src = ei;
    const int* dst = ei + E;

    size_t o = 0;
    auto alloc = [&](size_t bytes) {
        void* p = (char*)d_ws + o;
        o += (bytes + 255) / 256 * 256;
        return p;
    };
    int*           pcnt    = (int*)alloc((size_t)SBLOCKS * NB * 4);
    int*           btot    = (int*)alloc((size_t)NB * 4);
    int*           bbase   = (int*)alloc((size_t)(NB + 1) * 4);
    int*           off     = (int*)alloc((size_t)(N + 1) * 4);
    float*         dinv    = (float*)alloc((size_t)N * 4);
    unsigned int*  pairs   = (unsigned int*)alloc((size_t)E * 4);
    int*           col     = (int*)alloc((size_t)E * 4);
    unsigned char* T       = (unsigned char*)alloc((size_t)N * 64);
    float2*        qz      = (float2*)alloc((size_t)N * 8);
    float*         Wz      = (float*)alloc(128 * 4);
    float*         zc      = (float*)alloc(2 * 4);
    float*         pooled2 = (float*)alloc((size_t)N_GRAPHS * 2 * 4);

    // per-call zeroing of atomic targets (ws is not re-poisoned between replays)
    hipMemsetAsync(pooled2, 0, (size_t)N_GRAPHS * 2 * 4, stream);

    // CSR build: per-block histogram -> 2-level scan -> scatter -> per-bucket sort
    phist_kernel<<<SBLOCKS, 256, 0, stream>>>(dst, pcnt, E);
    pscanA_kernel<<<NB, 256, 0, stream>>>(pcnt, btot);
    pscanB_kernel<<<1, 512, 0, stream>>>(btot, bbase, off + N, E);
    scatter2_kernel<<<SBLOCKS, 256, 0, stream>>>(src, dst, pcnt, bbase, pairs, E);
    bucket_kernel<<<NB, 256, 0, stream>>>(pairs, bbase, col, off, dinv, N);

    // fold W2 @ Wl1 @ Wl2 -> Wz [64x2], constant zc [2]
    wz_kernel<<<1, 128, 0, stream>>>(W2, b2, Wl1, bl1, Wl2, bl2, Wz, zc);

    // layer 1: U = fp8(dinv * (x @ W1)) ; qz = dinv * relu(dinv*(sum+self)+b1) @ Wz
    lin_kernel<128><<<N / 32, 256, 0, stream>>>(x, W1, dinv, T);
    agg1_kernel<<<(N + 3) / 4, 256, 0, stream>>>(T, off, col, dinv, b1, Wz, qz, N);

    // layer 2 collapsed to 2 features + fused pooling
    agg2q_kernel<<<(N + 15) / 16, 256, 0, stream>>>(qz, off, col, dinv, pooled2, bat, N);

    // head: counts + mean + const + softmax over graphs
    head_kernel<<<1, 512, 0, stream>>>(pooled2, bat, zc, out, N);
}